// Round 6
// baseline (718.682 us; speedup 1.0000x reference)
//
#include <hip/hip_runtime.h>
#include <cstddef>

// B=2, C=256, W=H=64, N=4096, Cq=64
// outputs: res (2*256*4096) then attention (2*4096*4096), fp32

typedef __attribute__((ext_vector_type(8))) short bh8;   // 8 bf16 (4 VGPR)
typedef __attribute__((ext_vector_type(4))) short bh4;   // 4 bf16 (8B)
typedef __attribute__((ext_vector_type(4))) float f4;    // MFMA acc

static __device__ __forceinline__ short f2bf(float f) {
  unsigned u = __float_as_uint(f);
  unsigned r = (u + 0x7fffu + ((u >> 16) & 1u)) >> 16;
  return (short)r;
}
static __device__ __forceinline__ float bf2f(unsigned short s) {
  return __uint_as_float(((unsigned)s) << 16);
}

__device__ __forceinline__ float blk_sum256(float v, float* sm) {
#pragma unroll
  for (int o = 32; o > 0; o >>= 1) v += __shfl_down(v, o, 64);
  __syncthreads();
  if ((threadIdx.x & 63) == 0) sm[threadIdx.x >> 6] = v;
  __syncthreads();
  return sm[0] + sm[1] + sm[2] + sm[3];
}

__device__ __forceinline__ float blk_max256(float v, float* sm) {
#pragma unroll
  for (int o = 32; o > 0; o >>= 1) v = fmaxf(v, __shfl_down(v, o, 64));
  __syncthreads();
  if ((threadIdx.x & 63) == 0) sm[threadIdx.x >> 6] = v;
  __syncthreads();
  return fmaxf(fmaxf(sm[0], sm[1]), fmaxf(sm[2], sm[3]));
}

// swizzled LDS column (shorts): keeps 16B granules, spreads banks, no pad
#define SWCOL(row, col) ((col) ^ ((((row) >> 1) & 3) << 3))

// ==== spectral norm, parallel: t = W^T u ====
__global__ __launch_bounds__(256) void snA_kernel(
    const float* __restrict__ w1, const float* __restrict__ u1,
    const float* __restrict__ w2, const float* __restrict__ u2,
    const float* __restrict__ w3, const float* __restrict__ u3,
    float* __restrict__ t1, float* __restrict__ t2, float* __restrict__ t3) {
  int g = blockIdx.x * 256 + threadIdx.x;   // 0..7423
  const float* W; const float* u; float* t; int K; int j;
  if (g < 4608)      { W = w1; u = u1; t = t1; K = 4608; j = g; }
  else if (g < 6912) { W = w2; u = u2; t = t2; K = 2304; j = g - 4608; }
  else if (g < 7424) { W = w3; u = u3; t = t3; K = 512;  j = g - 6912; }
  else return;
  float a = 0.f;
  for (int i = 0; i < 256; ++i) a += W[(size_t)i * K + j] * u[i];
  t[j] = a;
}

// ==== invn[w] = 1/(||t||+eps) ====
__global__ __launch_bounds__(256) void snN_kernel(
    const float* __restrict__ t1, const float* __restrict__ t2,
    const float* __restrict__ t3, float* __restrict__ invn) {
  __shared__ float red[4];
  const float* t; int K;
  if (blockIdx.x == 0)      { t = t1; K = 4608; }
  else if (blockIdx.x == 1) { t = t2; K = 2304; }
  else                      { t = t3; K = 512;  }
  float ss = 0.f;
  for (int j = threadIdx.x; j < K; j += 256) { float v = t[j]; ss += v * v; }
  ss = blk_sum256(ss, red);
  if (threadIdx.x == 0) invn[blockIdx.x] = 1.0f / (sqrtf(ss) + 1e-12f);
}

// ==== st = W t (wave per row) ====
__global__ __launch_bounds__(256) void snB_kernel(
    const float* __restrict__ w1, const float* __restrict__ t1,
    const float* __restrict__ w2, const float* __restrict__ t2,
    const float* __restrict__ w3, const float* __restrict__ t3,
    float* __restrict__ st) {
  int blk = blockIdx.x;                // 192 blocks: w*64 + rowgrp
  int w = blk >> 6;
  const float* W; const float* t; int K;
  if (w == 0)      { W = w1; t = t1; K = 4608; }
  else if (w == 1) { W = w2; t = t2; K = 2304; }
  else             { W = w3; t = t3; K = 512;  }
  int lane = threadIdx.x & 63, wave = threadIdx.x >> 6;
  int row = (blk & 63) * 4 + wave;
  const float* Wr = W + (size_t)row * K;
  float a = 0.f;
  for (int j = lane; j < K; j += 64) a += Wr[j] * t[j];
#pragma unroll
  for (int o = 32; o > 0; o >>= 1) a += __shfl_down(a, o, 64);
  if (lane == 0) st[w * 256 + row] = a;
}

// ==== sigma -> inv_sig ====
__global__ __launch_bounds__(256) void snC_kernel(
    const float* __restrict__ st, const float* __restrict__ invn,
    float* __restrict__ inv_sig) {
  __shared__ float red[4];
  int w = blockIdx.x;
  float v = st[w * 256 + threadIdx.x];
  float ss = blk_sum256(v * v, red);
  if (threadIdx.x == 0) {
    float in = invn[w];
    float s2 = in * in * ss;            // ||s||^2
    float sn = in * sqrtf(ss);          // ||s||
    float sigma = s2 / (sn + 1e-12f);
    inv_sig[w] = 1.0f / sigma;
  }
}

// ---- cast x / pre to bf16 (same [c][n] layout) ----
__global__ __launch_bounds__(256) void cast_xp_kernel(
    const float* __restrict__ x, const float* __restrict__ pre,
    unsigned short* __restrict__ xb, unsigned short* __restrict__ pb) {
  int i = blockIdx.x * 256 + threadIdx.x;   // 8 elems per thread
  const float* s = blockIdx.y ? pre : x;
  unsigned short* d = blockIdx.y ? pb : xb;
  float4 v0 = ((const float4*)s)[i * 2];
  float4 v1 = ((const float4*)s)[i * 2 + 1];
  bh8 o = { f2bf(v0.x), f2bf(v0.y), f2bf(v0.z), f2bf(v0.w),
            f2bf(v1.x), f2bf(v1.y), f2bf(v1.z), f2bf(v1.w) };
  *(bh8*)&d[(size_t)i * 8] = o;
}

// ---- conv weights OIHW -> [tap][cichunk][co][ci32], bf16 (coalesced B-op) ----
__global__ __launch_bounds__(256) void transpose_w_kernel(
    const float* __restrict__ src, unsigned short* __restrict__ dst, int Cin) {
  int i = blockIdx.x * 256 + threadIdx.x;   // linear over 9*256*Cin
  int ciin = i & 31;
  int co = (i >> 5) & 255;
  int rest = i >> 13;                       // t*nchunk + cc
  int nchunk = Cin >> 5;
  int cc = rest % nchunk;
  int t = rest / nchunk;
  int ci = (cc << 5) + ciin;
  dst[i] = (unsigned short)f2bf(src[((size_t)co * Cin + ci) * 9 + t]);
}

// ---- cast by_w [256][512] to bf16 ----
__global__ __launch_bounds__(256) void cast_w3_kernel(
    const float* __restrict__ src, unsigned short* __restrict__ dst) {
  int i = blockIdx.x * 256 + threadIdx.x;   // 8 elems per thread
  float4 v0 = ((const float4*)src)[i * 2];
  float4 v1 = ((const float4*)src)[i * 2 + 1];
  bh8 o = { f2bf(v0.x), f2bf(v0.y), f2bf(v0.z), f2bf(v0.w),
            f2bf(v1.x), f2bf(v1.y), f2bf(v1.z), f2bf(v1.w) };
  *(bh8*)&dst[(size_t)i * 8] = o;
}

// ---- fused q = qw*x (1x1 conv) -> qt [n][64] bf16, MFMA ----
// Per block: 64 n-rows, full cq=64, K=256 split 4 waves x 64c (2 chunks).
// A = x^T staged via scalar LDS transpose; B = qw cast inline to bf16.
// Replaces the scalar-VALU qconv (537 MB L3 re-reads) + qtrans pair.
__global__ __launch_bounds__(256, 2) void qgemm_kernel(
    const unsigned short* __restrict__ xb, const float* __restrict__ qw,
    unsigned short* __restrict__ qt) {
  int b = blockIdx.y;
  int n0 = blockIdx.x * 64;
  __shared__ short smem[24576];      // 48 KB (staging 32 KB; reduce reuse)
  int tid = threadIdx.x;
  int wave = tid >> 6, lane = tid & 63;
  short* Wt = smem + wave * 4096;
  short* Xt = Wt + 2048;
  int ln = lane & 15, qd = lane >> 4;
  int part = lane & 3, r4 = lane >> 2;
  int cl = lane >> 1, ng = lane & 1;
  f4 z = {0.f, 0.f, 0.f, 0.f};
  f4 acc[4][4];
#pragma unroll
  for (int i = 0; i < 4; ++i)
#pragma unroll
    for (int j = 0; j < 4; ++j) acc[i][j] = z;
#pragma unroll
  for (int kc = 0; kc < 2; ++kc) {
    int cc = wave * 2 + kc;
    int c0c = cc << 5;
    // stage weight chunk [cq=64][c=32] bf16 (cast f32 inline)
#pragma unroll
    for (int t2 = 0; t2 < 4; ++t2) {
      int rr = r4 + t2 * 16;
      const float* wp = &qw[rr * 256 + c0c + part * 8];
      float4 v0 = *(const float4*)wp;
      float4 v1 = *(const float4*)(wp + 4);
      bh8 o = { f2bf(v0.x), f2bf(v0.y), f2bf(v0.z), f2bf(v0.w),
                f2bf(v1.x), f2bf(v1.y), f2bf(v1.z), f2bf(v1.w) };
      *(bh8*)&Wt[rr * 32 + SWCOL(rr, part * 8)] = o;
    }
    // stage x^T chunk [n=64][c=32] via scalar transpose (reads coalesced)
#pragma unroll
    for (int it = 0; it < 4; ++it) {
      int gg = ng + it * 2;
      bh8 v = *(const bh8*)&xb[((size_t)(b * 256 + c0c + cl) << 12) + n0 + gg * 8];
#pragma unroll
      for (int e = 0; e < 8; ++e) {
        int nl = gg * 8 + e;
        Xt[nl * 32 + (cl ^ (((nl >> 1) & 3) << 3))] = v[e];
      }
    }
    // wave-synchronous MFMA (same-wave ds_write -> ds_read)
    bh8 bw[4];
#pragma unroll
    for (int j = 0; j < 4; ++j) {
      int row = j * 16 + ln;
      bw[j] = *(const bh8*)&Wt[row * 32 + SWCOL(row, qd * 8)];
    }
#pragma unroll
    for (int i = 0; i < 4; ++i) {
      int row = i * 16 + ln;
      bh8 a = *(const bh8*)&Xt[row * 32 + SWCOL(row, qd * 8)];
#pragma unroll
      for (int j = 0; j < 4; ++j)
        acc[i][j] = __builtin_amdgcn_mfma_f32_16x16x32_bf16(a, bw[j], acc[i][j], 0, 0, 0);
    }
  }
  // cross-wave reduction: wave j owns cq subtile j
  float* red = (float*)smem;
  __syncthreads();
#pragma unroll
  for (int j = 0; j < 4; ++j) {
    if (j == wave) continue;
    int s = wave - (wave > j ? 1 : 0);
#pragma unroll
    for (int i = 0; i < 4; ++i)
      *(f4*)&red[((((j * 3 + s) << 2) + i) << 8) + (lane << 2)] = acc[i][j];
  }
  __syncthreads();
#pragma unroll
  for (int j = 0; j < 4; ++j) {
    if (j != wave) continue;
#pragma unroll
    for (int s = 0; s < 3; ++s)
#pragma unroll
      for (int i = 0; i < 4; ++i) {
        f4 v = *(const f4*)&red[((((j * 3 + s) << 2) + i) << 8) + (lane << 2)];
        acc[i][j][0] += v[0]; acc[i][j][1] += v[1];
        acc[i][j][2] += v[2]; acc[i][j][3] += v[3];
      }
  }
  // epilogue: qt[b][n][cq], wave writes cq subtile == wave
#pragma unroll
  for (int j = 0; j < 4; ++j) {
    if (j != wave) continue;
#pragma unroll
    for (int i = 0; i < 4; ++i) {
      int n = n0 + i * 16 + qd * 4;
#pragma unroll
      for (int r = 0; r < 4; ++r)
        qt[((size_t)(b * 4096 + n + r) << 6) + j * 16 + ln] =
            (unsigned short)f2bf(acc[i][j][r]);
    }
  }
}

// ---- energy via MFMA bf16: 128x128 tile, 4 waves (2x2), K=64 ----
__global__ __launch_bounds__(256, 4) void energy_mfma_kernel(
    const unsigned short* __restrict__ qt, float* __restrict__ att) {
  int b = blockIdx.z;
  int n0 = blockIdx.x << 7;
  int m0 = blockIdx.y << 7;
  __shared__ short Qn[128 * 64];
  __shared__ short Qm[128 * 64];
  int tid = threadIdx.x;
  int wave = tid >> 6, lane = tid & 63;
  int ln = lane & 15, qd = lane >> 4;
  int wy = wave >> 1, wx = wave & 1;
  int g = tid & 7, row0 = tid >> 3;         // 8 granules x 32 rows
#pragma unroll
  for (int it = 0; it < 4; ++it) {
    int r = row0 + it * 32;
    int colb = ((g ^ (r & 7)) << 3);
    *(bh8*)&Qn[(r << 6) + colb] =
        *(const bh8*)&qt[((size_t)(b * 4096 + n0 + r) << 6) + (g << 3)];
    *(bh8*)&Qm[(r << 6) + colb] =
        *(const bh8*)&qt[((size_t)(b * 4096 + m0 + r) << 6) + (g << 3)];
  }
  __syncthreads();
  f4 z = {0.f, 0.f, 0.f, 0.f};
  f4 acc[4][4];
#pragma unroll
  for (int i = 0; i < 4; ++i)
#pragma unroll
    for (int j = 0; j < 4; ++j) acc[i][j] = z;
#pragma unroll
  for (int kc = 0; kc < 2; ++kc) {
    bh8 am[4];
#pragma unroll
    for (int j = 0; j < 4; ++j) {
      int row = wx * 64 + j * 16 + ln;
      int colb = (((qd + (kc << 2)) ^ (row & 7)) << 3);
      am[j] = *(const bh8*)&Qm[(row << 6) + colb];
    }
#pragma unroll
    for (int i = 0; i < 4; ++i) {
      int row = wy * 64 + i * 16 + ln;
      int colb = (((qd + (kc << 2)) ^ (row & 7)) << 3);
      bh8 an = *(const bh8*)&Qn[(row << 6) + colb];
#pragma unroll
      for (int j = 0; j < 4; ++j)
        acc[i][j] = __builtin_amdgcn_mfma_f32_16x16x32_bf16(an, am[j], acc[i][j], 0, 0, 0);
    }
  }
  size_t base = ((size_t)b << 24);
#pragma unroll
  for (int i = 0; i < 4; ++i) {
    int n = n0 + wy * 64 + i * 16 + qd * 4;
#pragma unroll
    for (int j = 0; j < 4; ++j) {
      int m = m0 + wx * 64 + j * 16 + ln;
#pragma unroll
      for (int r = 0; r < 4; ++r)
        att[base + (((size_t)(n + r)) << 12) + m] = acc[i][j][r];
    }
  }
}

// ---- softmax in place over last dim 4096 ----
__global__ __launch_bounds__(256) void softmax_kernel(float* __restrict__ att) {
  __shared__ float red[4];
  size_t row = blockIdx.x;
  float4* rp4 = (float4*)(att + (row << 12));
  int tid = threadIdx.x;
  float4 v[4];
#pragma unroll
  for (int i = 0; i < 4; ++i) v[i] = rp4[tid + (i << 8)];
  float mx = -INFINITY;
#pragma unroll
  for (int i = 0; i < 4; ++i)
    mx = fmaxf(mx, fmaxf(fmaxf(v[i].x, v[i].y), fmaxf(v[i].z, v[i].w)));
  mx = blk_max256(mx, red);
  float s = 0.f;
#pragma unroll
  for (int i = 0; i < 4; ++i) {
    v[i].x = __expf(v[i].x - mx); v[i].y = __expf(v[i].y - mx);
    v[i].z = __expf(v[i].z - mx); v[i].w = __expf(v[i].w - mx);
    s += v[i].x + v[i].y + v[i].z + v[i].w;
  }
  s = blk_sum256(s, red);
  float inv = 1.0f / s;
#pragma unroll
  for (int i = 0; i < 4; ++i) {
    v[i].x *= inv; v[i].y *= inv; v[i].z *= inv; v[i].w *= inv;
    rp4[tid + (i << 8)] = v[i];
  }
}

// ---- fused out/cf MFMA GEMM: 4 waves, k-split, 2-deep bf16 att prefetch ----
// 1-D grid of EXACTLY 512 blocks (r5 crashed with 1024: j0 OOB). bid&7
// selects (c0,b) so the 64 j-tiles sharing one xb/pb working set (4.2 MB)
// land on one XCD's L2. launch_bounds(256,2): no spill (r1 lesson).
__global__ __launch_bounds__(256, 2) void outcf_mfma_kernel(
    const unsigned short* __restrict__ xb, const unsigned short* __restrict__ pb,
    const float* __restrict__ x, const float* __restrict__ pre,
    const float* __restrict__ att, const float* __restrict__ mask,
    const float* __restrict__ gamma_p, const float* __restrict__ alpha_p,
    unsigned short* __restrict__ y_t) {
  int bid = blockIdx.x;
  int grp = bid & 7;                  // XCD id heuristic: wgid % 8
  int b = grp >> 2;
  int c0 = (grp & 3) * 64;
  int j0 = (bid >> 3) * 64;
  __shared__ short smem[12 * 64 * 32];   // 49152 B: 4 waves x (Xs,Ps,As) 64x32
  int tid = threadIdx.x;
  int wave = tid >> 6, lane = tid & 63;
  short* Xs = smem + wave * (3 * 2048);
  short* Ps = Xs + 2048;
  short* As = Ps + 2048;
  int ln = lane & 15, qd = lane >> 4;
  f4 z = {0.f, 0.f, 0.f, 0.f};
  f4 accO[4][4], accC[4][4];
#pragma unroll
  for (int i = 0; i < 4; ++i)
#pragma unroll
    for (int j = 0; j < 4; ++j) { accO[i][j] = z; accC[i][j] = z; }
  int part = lane & 3, r4 = lane >> 2;
  int part8 = lane & 7, r8 = lane >> 3;
  int kb = wave << 10;                       // 1024 k per wave
  size_t abase = ((size_t)b << 24);
  bh8 xr[4], pr[4];
  bh4 arA[8], arB[8];                        // 2-deep att prefetch, bf16
  // prologue: xr/pr @kb, arA @kb, arB @kb+32
#pragma unroll
  for (int t2 = 0; t2 < 4; ++t2) {
    int rr = r4 + t2 * 16;
    xr[t2] = *(const bh8*)&xb[((size_t)(b * 256 + c0 + rr) << 12) + kb + part * 8];
    pr[t2] = *(const bh8*)&pb[((size_t)(b * 256 + c0 + rr) << 12) + kb + part * 8];
  }
#pragma unroll
  for (int t2 = 0; t2 < 8; ++t2) {
    int rr = r8 + t2 * 8;
    float4 v = *(const float4*)&att[abase + ((size_t)(j0 + rr) << 12) + kb + part8 * 4];
    bh4 o = { f2bf(v.x), f2bf(v.y), f2bf(v.z), f2bf(v.w) };
    arA[t2] = o;
  }
#pragma unroll
  for (int t2 = 0; t2 < 8; ++t2) {
    int rr = r8 + t2 * 8;
    float4 v = *(const float4*)&att[abase + ((size_t)(j0 + rr) << 12) + kb + 32 + part8 * 4];
    bh4 o = { f2bf(v.x), f2bf(v.y), f2bf(v.z), f2bf(v.w) };
    arB[t2] = o;
  }
  for (int it = 0; it < 32; it += 2) {
    int kA = kb + (it << 5);
    // ---- phase A (k = kA, data in xr/pr/arA) ----
#pragma unroll
    for (int t2 = 0; t2 < 4; ++t2) {
      int rr = r4 + t2 * 16;
      int col = SWCOL(rr, part * 8);
      *(bh8*)&Xs[rr * 32 + col] = xr[t2];
      *(bh8*)&Ps[rr * 32 + col] = pr[t2];
    }
#pragma unroll
    for (int t2 = 0; t2 < 8; ++t2) {
      int rr = r8 + t2 * 8;
      *(bh4*)&As[rr * 32 + SWCOL(rr, part8 * 4)] = arA[t2];
    }
    {
      int k1 = kA + 32;
#pragma unroll
      for (int t2 = 0; t2 < 4; ++t2) {
        int rr = r4 + t2 * 16;
        xr[t2] = *(const bh8*)&xb[((size_t)(b * 256 + c0 + rr) << 12) + k1 + part * 8];
        pr[t2] = *(const bh8*)&pb[((size_t)(b * 256 + c0 + rr) << 12) + k1 + part * 8];
      }
    }
    if (it + 2 < 32) {
      int k2 = kA + 64;
#pragma unroll
      for (int t2 = 0; t2 < 8; ++t2) {
        int rr = r8 + t2 * 8;
        float4 v = *(const float4*)&att[abase + ((size_t)(j0 + rr) << 12) + k2 + part8 * 4];
        bh4 o = { f2bf(v.x), f2bf(v.y), f2bf(v.z), f2bf(v.w) };
        arA[t2] = o;
      }
    }
    {
      bh8 bf[4];
#pragma unroll
      for (int j = 0; j < 4; ++j) {
        int row = j * 16 + ln;
        bf[j] = *(const bh8*)&As[row * 32 + SWCOL(row, qd * 8)];
      }
#pragma unroll
      for (int i = 0; i < 4; ++i) {
        int row = i * 16 + ln;
        int col = SWCOL(row, qd * 8);
        bh8 ax = *(const bh8*)&Xs[row * 32 + col];
        bh8 ap = *(const bh8*)&Ps[row * 32 + col];
#pragma unroll
        for (int j = 0; j < 4; ++j) {
          accO[i][j] = __builtin_amdgcn_mfma_f32_16x16x32_bf16(ax, bf[j], accO[i][j], 0, 0, 0);
          accC[i][j] = __builtin_amdgcn_mfma_f32_16x16x32_bf16(ap, bf[j], accC[i][j], 0, 0, 0);
        }
      }
    }
    // ---- phase B (k = kA+32, data in xr/pr/arB) ----
    int kB = kA + 32;
#pragma unroll
    for (int t2 = 0; t2 < 4; ++t2) {
      int rr = r4 + t2 * 16;
      int col = SWCOL(rr, part * 8);
      *(bh8*)&Xs[rr * 32 + col] = xr[t2];
      *(bh8*)&Ps[rr * 32 + col] = pr[t2];
    }
#pragma unroll
    for (int t2 = 0; t2 < 8; ++t2) {
      int rr = r8 + t2 * 8;
      *(bh4*)&As[rr * 32 + SWCOL(rr, part8 * 4)] = arB[t2];
    }
    if (it + 2 < 32) {
      int k1 = kB + 32;
#pragma unroll
      for (int t2 = 0; t2 < 4; ++t2) {
        int rr = r4 + t2 * 16;
        xr[t2] = *(const bh8*)&xb[((size_t)(b * 256 + c0 + rr) << 12) + k1 + part * 8];
        pr[t2] = *(const bh8*)&pb[((size_t)(b * 256 + c0 + rr) << 12) + k1 + part * 8];
      }
    }
    if (it + 3 < 32) {
      int k2 = kB + 64;
#pragma unroll
      for (int t2 = 0; t2 < 8; ++t2) {
        int rr = r8 + t2 * 8;
        float4 v = *(const float4*)&att[abase + ((size_t)(j0 + rr) << 12) + k2 + part8 * 4];
        bh4 o = { f2bf(v.x), f2bf(v.y), f2bf(v.z), f2bf(v.w) };
        arB[t2] = o;
      }
    }
    {
      bh8 bf[4];
#pragma unroll
      for (int j = 0; j < 4; ++j) {
        int row = j * 16 + ln;
        bf[j] = *(const bh8*)&As[row * 32 + SWCOL(row, qd * 8)];
      }
#pragma unroll
      for (int i = 0; i < 4; ++i) {
        int row = i * 16 + ln;
        int col = SWCOL(row, qd * 8);
        bh8 ax = *(const bh8*)&Xs[row * 32 + col];
        bh8 ap = *(const bh8*)&Ps[row * 32 + col];
#pragma unroll
        for (int j = 0; j < 4; ++j) {
          accO[i][j] = __builtin_amdgcn_mfma_f32_16x16x32_bf16(ax, bf[j], accO[i][j], 0, 0, 0);
          accC[i][j] = __builtin_amdgcn_mfma_f32_16x16x32_bf16(ap, bf[j], accC[i][j], 0, 0, 0);
        }
      }
    }
  }
  // ---- cross-wave k-reduction: wave j owns column block j ----
  float* red = (float*)smem;
  __syncthreads();
#pragma unroll
  for (int j = 0; j < 4; ++j) {
    if (j == wave) continue;
    int s = wave - (wave > j ? 1 : 0);
#pragma unroll
    for (int i = 0; i < 4; ++i)
      *(f4*)&red[((((j * 3 + s) << 2) + i) << 8) + (lane << 2)] = accO[i][j];
  }
  __syncthreads();
#pragma unroll
  for (int j = 0; j < 4; ++j) {
    if (j != wave) continue;
#pragma unroll
    for (int s = 0; s < 3; ++s)
#pragma unroll
      for (int i = 0; i < 4; ++i) {
        f4 v = *(const f4*)&red[((((j * 3 + s) << 2) + i) << 8) + (lane << 2)];
        accO[i][j][0] += v[0]; accO[i][j][1] += v[1];
        accO[i][j][2] += v[2]; accO[i][j][3] += v[3];
      }
  }
  __syncthreads();
#pragma unroll
  for (int j = 0; j < 4; ++j) {
    if (j == wave) continue;
    int s = wave - (wave > j ? 1 : 0);
#pragma unroll
    for (int i = 0; i < 4; ++i)
      *(f4*)&red[((((j * 3 + s) << 2) + i) << 8) + (lane << 2)] = accC[i][j];
  }
  __syncthreads();
#pragma unroll
  for (int j = 0; j < 4; ++j) {
    if (j != wave) continue;
#pragma unroll
    for (int s = 0; s < 3; ++s)
#pragma unroll
      for (int i = 0; i < 4; ++i) {
        f4 v = *(const f4*)&red[((((j * 3 + s) << 2) + i) << 8) + (lane << 2)];
        accC[i][j][0] += v[0]; accC[i][j][1] += v[1];
        accC[i][j][2] += v[2]; accC[i][j][3] += v[3];
      }
  }
  // ---- epilogue: wave handles j == wave ----
  float g = gamma_p[0], al = alpha_p[0];
#pragma unroll
  for (int j = 0; j < 4; ++j) {
    if (j != wave) continue;
    int jp = j0 + j * 16 + ln;
    float mv = mask[(b << 12) + jp];
#pragma unroll
    for (int i = 0; i < 4; ++i) {
      int cb = c0 + i * 16 + qd * 4;
      bh4 oY, oC;
#pragma unroll
      for (int r = 0; r < 4; ++r) {
        float xo = x[((size_t)(b * 256 + cb + r) << 12) + jp];
        float po = pre[((size_t)(b * 256 + cb + r) << 12) + jp];
        oY[r] = f2bf(g * accO[i][j][r] + xo);
        oC[r] = f2bf(al * (1.f - mv) * accC[i][j][r] + mv * po);
      }
      size_t rowb = ((size_t)b * 4096 + jp) * 512;
      *(bh4*)&y_t[rowb + cb] = oY;
      *(bh4*)&y_t[rowb + 256 + cb] = oC;
    }
  }
}

// ---- BN stats phase 1 ----
__global__ __launch_bounds__(256) void bn_part_kernel(
    const void* __restrict__ src, int isbf, int C, int rows_per_slab,
    float* __restrict__ part) {
  int slab = blockIdx.x;
  int r0 = slab * rows_per_slab;
  for (int co = threadIdx.x; co < C; co += 256) {
    float s = 0.f, ss = 0.f;
    if (isbf) {
      const unsigned short* p = (const unsigned short*)src;
      for (int r = 0; r < rows_per_slab; ++r) {
        float v = bf2f(p[(size_t)(r0 + r) * C + co]); s += v; ss += v * v;
      }
    } else {
      const float* p = (const float*)src;
      for (int r = 0; r < rows_per_slab; ++r) {
        float v = p[(size_t)(r0 + r) * C + co]; s += v; ss += v * v;
      }
    }
    part[(size_t)(slab * 2) * C + co] = s;
    part[(size_t)(slab * 2 + 1) * C + co] = ss;
  }
}

// ---- BN stats phase 2 ----
__global__ __launch_bounds__(256) void bn_finish_kernel(
    const float* __restrict__ part, int C, int slabs, float inv_count,
    float* __restrict__ mean, float* __restrict__ rstd) {
  for (int co = threadIdx.x; co < C; co += 256) {
    float s = 0.f, ss = 0.f;
    for (int sl = 0; sl < slabs; ++sl) {
      s += part[(size_t)(sl * 2) * C + co];
      ss += part[(size_t)(sl * 2 + 1) * C + co];
    }
    float m = s * inv_count;
    float var = ss * inv_count - m * m;
    mean[co] = m;
    rstd[co] = rsqrtf(var + 1e-5f);
  }
}

// ---- BN apply + leaky, bf16 -> bf16 ([n][C] layout) ----
__global__ __launch_bounds__(256) void bn_act_bf_kernel(
    const unsigned short* __restrict__ src, unsigned short* __restrict__ dst,
    const float* __restrict__ mean, const float* __restrict__ rstd,
    const float* __restrict__ sc, const float* __restrict__ bi, int Cm1) {
  int i = blockIdx.x * 256 + threadIdx.x;   // 4 elems
  int ch = (i * 4) & Cm1;
  bh4 v = *(const bh4*)&src[(size_t)i * 4];
  bh4 o;
#pragma unroll
  for (int e = 0; e < 4; ++e) {
    int c = ch + e;
    float a = rstd[c] * sc[c];
    float bb = bi[c] - mean[c] * a;
    float f = bf2f((unsigned short)v[e]) * a + bb;
    f = f > 0.f ? f : 0.01f * f;
    o[e] = f2bf(f);
  }
  *(bh4*)&dst[(size_t)i * 4] = o;
}

// ---- BN apply + leaky, f32 -> bf16 ----
__global__ __launch_bounds__(256) void bn_act_f_kernel(
    const float* __restrict__ src, unsigned short* __restrict__ dst,
    const float* __restrict__ mean, const float* __restrict__ rstd,
    const float* __restrict__ sc, const float* __restrict__ bi, int Cm1) {
  int i = blockIdx.x * 256 + threadIdx.x;   // 4 elems
  int ch = (i * 4) & Cm1;
  float4 v = ((const float4*)src)[i];
  float vv[4] = {v.x, v.y, v.z, v.w};
  bh4 o;
#pragma unroll
  for (int e = 0; e < 4; ++e) {
    int c = ch + e;
    float a = rstd[c] * sc[c];
    float bb = bi[c] - mean[c] * a;
    float f = vv[e] * a + bb;
    f = f > 0.f ? f : 0.01f * f;
    o[e] = f2bf(f);
  }
  *(bh4*)&dst[(size_t)i * 4] = o;
}

// ---- 3x3 conv: 9 accumulated MFMA GEMMs, 4 waves k-split, T14 prefetch ----
// (256,2): grid=512 is already 2 blocks/CU, so the looser VGPR cap is free
// headroom for the 13 staged act regs + weight double-buffer (no spill).
__global__ __launch_bounds__(256, 2) void conv3x3_mfma_kernel(
    const unsigned short* __restrict__ act_t, const unsigned short* __restrict__ wt,
    const float* __restrict__ inv_sig, int sidx, int Cin, int mode,
    float* __restrict__ out) {
  int b = blockIdx.z;
  int co0 = blockIdx.y * 64;
  int n0 = blockIdx.x * 64;
  __shared__ short smem[4 * 194 * 32];   // 49664 B, per-wave act tiles
  int tid = threadIdx.x;
  int wave = tid >> 6, lane = tid & 63;
  short* act_s = smem + wave * (194 * 32);
  int ln = lane & 15, qd = lane >> 4;
  int part = lane & 3, r4 = lane >> 2;
  f4 z = {0.f, 0.f, 0.f, 0.f};
  f4 acc[4][4];
#pragma unroll
  for (int i = 0; i < 4; ++i)
#pragma unroll
    for (int j = 0; j < 4; ++j) acc[i][j] = z;
  bh8 zf = {};
  int nchunk = Cin >> 5;
  int per = nchunk >> 2;                 // chunks per wave
  size_t tstride = (size_t)nchunk * 256 * 32;   // weight tap stride
  int cc0 = wave * per;
  bh8 sreg[13];
  // prologue: prefetch chunk cc0 act into regs
#pragma unroll
  for (int it = 0; it < 13; ++it) {
    int rr = r4 + it * 16;
    bh8 v = {};
    if (rr < 194) {
      int flat = n0 - 65 + rr;
      if ((unsigned)flat < 4096u)
        v = *(const bh8*)&act_t[((size_t)(b * 4096 + flat)) * Cin + (cc0 << 5) + part * 8];
    }
    sreg[it] = v;
  }
  for (int itc = 0; itc < per; ++itc) {
    int cc = cc0 + itc;
    // write staged act to LDS (wave-synchronous, no barrier)
#pragma unroll
    for (int it = 0; it < 13; ++it) {
      int rr = r4 + it * 16;
      if (rr < 194)
        *(bh8*)&act_s[rr * 32 + SWCOL(rr, part * 8)] = sreg[it];
    }
    // issue next chunk's act loads (hidden under the 9-tap MFMA loop)
    if (itc + 1 < per) {
      int ci0n = (cc + 1) << 5;
#pragma unroll
      for (int it = 0; it < 13; ++it) {
        int rr = r4 + it * 16;
        bh8 v = {};
        if (rr < 194) {
          int flat = n0 - 65 + rr;
          if ((unsigned)flat < 4096u)
            v = *(const bh8*)&act_t[((size_t)(b * 4096 + flat)) * Cin + ci0n + part * 8];
        }
        sreg[it] = v;
      }
    }
    // weights: [t][cc][co][ci32] layout, contiguous per (t,cc,j)
    const unsigned short* wb0 = wt + ((size_t)cc * 256) * 32;
    bh8 bwc[4], bwn[4];
#pragma unroll
    for (int j = 0; j < 4; ++j)
      bwc[j] = *(const bh8*)&wb0[(size_t)(co0 + j * 16 + ln) * 32 + qd * 8];
#pragma unroll
    for (int t = 0; t < 9; ++t) {
      if (t < 8) {
        const unsigned short* wbn = wb0 + (size_t)(t + 1) * tstride;
#pragma unroll
        for (int j = 0; j < 4; ++j)
          bwn[j] = *(const bh8*)&wbn[(size_t)(co0 + j * 16 + ln) * 32 + qd * 8];
      }
      int dy = t / 3, dx = t - dy * 3;
      int off = (dy - 1) * 64 + (dx - 1);
#pragma unroll
      for (int i = 0; i < 4; ++i) {
        int px = i * 16 + ln;
        int row = 65 + off + px;
        bh8 a = *(const bh8*)&act_s[row * 32 + SWCOL(row, qd * 8)];
        if (dx == 0 && px == 0) a = zf;
        if (dx == 2 && px == 63) a = zf;
#pragma unroll
        for (int j = 0; j < 4; ++j)
          acc[i][j] = __builtin_amdgcn_mfma_f32_16x16x32_bf16(a, bwc[j], acc[i][j], 0, 0, 0);
      }
      if (t < 8) {
#pragma unroll
        for (int j = 0; j < 4; ++j) bwc[j] = bwn[j];
      }
    }
  }
  // ---- cross-wave reduction: wave j owns column block j ----
  float* red = (float*)smem;
  __syncthreads();
#pragma unroll
  for (int j = 0; j < 4; ++j) {
    if (j == wave) continue;
    int s = wave - (wave > j ? 1 : 0);
#pragma unroll
    for (int i = 0; i < 4; ++i)
      *(f4*)&red[((((j * 3 + s) << 2) + i) << 8) + (lane << 2)] = acc[i][j];
  }
  __syncthreads();
#pragma unroll
  for (int j = 0; j < 4; ++j) {
    if (j != wave) continue;
#pragma unroll
    for (int s = 0; s < 3; ++s)
#pragma unroll
      for (int i = 0; i < 4; ++i) {
        f4 v = *(const f4*)&red[((((j * 3 + s) << 2) + i) << 8) + (lane << 2)];
        acc[i][j][0] += v[0]; acc[i][j][1] += v[1];
        acc[i][j][2] += v[2]; acc[i][j][3] += v[3];
      }
  }
  float isg = inv_sig[sidx];
  if (mode == 0) {
#pragma unroll
    for (int j = 0; j < 4; ++j) {
      if (j != wave) continue;
      int co = co0 + j * 16 + ln;
#pragma unroll
      for (int i = 0; i < 4; ++i) {
        int pb = n0 + i * 16 + qd * 4;
#pragma unroll
        for (int r = 0; r < 4; ++r)
          out[((size_t)(b * 4096 + pb + r)) * 256 + co] = acc[i][j][r] * isg;
      }
    }
  } else {
#pragma unroll
    for (int j = 0; j < 4; ++j) {
      if (j != wave) continue;
      int co = co0 + j * 16 + ln;
#pragma unroll
      for (int i = 0; i < 4; ++i) {
        int pb = n0 + i * 16 + qd * 4;
        float4* rp = (float4*)&out[((size_t)(b * 256 + co) << 12) + pb];
        float4 v = *rp;
        v.x += acc[i][j][0] * isg; v.y += acc[i][j][1] * isg;
        v.z += acc[i][j][2] * isg; v.w += acc[i][j][3] * isg;
        *rp = v;
      }
    }
  }
}

// ---- shortcut 1x1, 4 waves split K=512, T14 prefetch ----
__global__ __launch_bounds__(256, 2) void scgemm_mfma_kernel(
    const unsigned short* __restrict__ y_t, const unsigned short* __restrict__ w3b,
    const float* __restrict__ inv_sig, float* __restrict__ res) {
  int b = blockIdx.z;
  int co0 = blockIdx.y * 64;
  int n0 = blockIdx.x * 64;
  __shared__ short smem[24576];          // 49152 B (staging uses first 16 KB)
  int tid = threadIdx.x;
  int wave = tid >> 6, lane = tid & 63;
  short* Ys = smem + wave * 2048;
  int ln = lane & 15, qd = lane >> 4;
  int part = lane & 3, r4 = lane >> 2;
  f4 z = {0.f, 0.f, 0.f, 0.f};
  f4 acc[4][4];
#pragma unroll
  for (int i = 0; i < 4; ++i)
#pragma unroll
    for (int j = 0; j < 4; ++j) acc[i][j] = z;
  int kb = wave << 7;                    // 128 k per wave
  bh8 ys[4], bwc[4], yn[4], bwn[4];
#pragma unroll
  for (int t2 = 0; t2 < 4; ++t2) {
    int rr = r4 + t2 * 16;
    ys[t2] = *(const bh8*)&y_t[((size_t)(b * 4096 + n0 + rr)) * 512 + kb + part * 8];
  }
#pragma unroll
  for (int j = 0; j < 4; ++j)
    bwc[j] = *(const bh8*)&w3b[((size_t)(co0 + j * 16 + ln)) * 512 + kb + qd * 8];
#pragma unroll
  for (int it = 0; it < 4; ++it) {
    int k0 = kb + (it << 5);
#pragma unroll
    for (int t2 = 0; t2 < 4; ++t2) {
      int rr = r4 + t2 * 16;
      *(bh8*)&Ys[rr * 32 + SWCOL(rr, part * 8)] = ys[t2];
    }
    if (it < 3) {
      int k1 = k0 + 32;
#pragma unroll
      for (int t2 = 0; t2 < 4; ++t2) {
        int rr = r4 + t2 * 16;
        yn[t2] = *(const bh8*)&y_t[((size_t)(b * 4096 + n0 + rr)) * 512 + k1 + part * 8];
      }
#pragma unroll
      for (int j = 0; j < 4; ++j)
        bwn[j] = *(const bh8*)&w3b[((size_t)(co0 + j * 16 + ln)) * 512 + k1 + qd * 8];
    }
#pragma unroll
    for (int i = 0; i < 4; ++i) {
      int row = i * 16 + ln;
      bh8 a = *(const bh8*)&Ys[row * 32 + SWCOL(row, qd * 8)];
#pragma unroll
      for (int j = 0; j < 4; ++j)
        acc[i][j] = __builtin_amdgcn_mfma_f32_16x16x32_bf16(a, bwc[j], acc[i][j], 0, 0, 0);
    }
    if (it < 3) {
#pragma unroll
      for (int t2 = 0; t2 < 4; ++t2) ys[t2] = yn[t2];
#pragma unroll
      for (int j = 0; j < 4; ++j) bwc[j] = bwn[j];
    }
  }
  // ---- cross-wave reduction: wave j owns column block j ----
  float* red = (float*)smem;
  __syncthreads();
#pragma unroll
  for (int j = 0; j < 4; ++j) {
    if (j == wave) continue;
    int s = wave - (wave > j ? 1 : 0);
#pragma unroll
    for (int i = 0; i < 4; ++i)
      *(f4*)&red[((((j * 3 + s) << 2) + i) << 8) + (lane << 2)] = acc[i][j];
  }
  __syncthreads();
#pragma unroll
  for (int j = 0; j < 4; ++j) {
    if (j != wave) continue;
#pragma unroll
    for (int s = 0; s < 3; ++s)
#pragma unroll
      for (int i = 0; i < 4; ++i) {
        f4 v = *(const f4*)&red[((((j * 3 + s) << 2) + i) << 8) + (lane << 2)];
        acc[i][j][0] += v[0]; acc[i][j][1] += v[1];
        acc[i][j][2] += v[2]; acc[i][j][3] += v[3];
      }
  }
  float isg = inv_sig[2];
#pragma unroll
  for (int j = 0; j < 4; ++j) {
    if (j != wave) continue;
    int co = co0 + j * 16 + ln;
#pragma unroll
    for (int i = 0; i < 4; ++i) {
      int pb = n0 + i * 16 + qd * 4;
      float4 o;
      o.x = acc[i][j][0] * isg; o.y = acc[i][j][1] * isg;
      o.z = acc[i][j][2] * isg; o.w = acc[i][j][3] * isg;
      *(float4*)&res[((size_t)(b * 256 + co) << 12) + pb] = o;
    }
  }
}

extern "C" void kernel_launch(void* const* d_in, const int* in_sizes, int n_in,
                              void* d_out, int out_size, void* d_ws, size_t ws_size,
                              hipStream_t stream) {
  const float* x     = (const float*)d_in[0];
  const float* pre   = (const float*)d_in[1];
  const float* mask  = (const float*)d_in[2];
  const float* qw    = (const float*)d_in[3];
  const float* gamma = (const float*)d_in[4];
  const float* alpha = (const float*)d_in[5];
  const float* bn1s  = (const float*)d_in[6];
  const float* bn1b  = (const float*)d_in[7];
  const float* c1w   = (const float*)d_in[8];
  const float* u1    = (const float*)d_in[9];
  const float* bn2s  = (const float*)d_in[11];
  const float* bn2b  = (const float*)d_in[12];
  const float* c2w   = (const float*)d_in[13];
  const float* u2    = (const float*)d_in[14];
  const float* byw   = (const float*)d_in[16];
  const float* u3    = (const float*)d_in[17];

  float* res = (float*)d_out;                 // 2*256*4096
  float* att = res + (size_t)2 * 256 * 4096;  // 2*4096*4096

  char* W = (char*)d_ws;
  float* inv_sig = (float*)(W + 0);
  float* mean1   = (float*)(W + 64);
  float* rstd1   = (float*)(W + 2112);
  float* mean2   = (float*)(W + 4160);
  float* rstd2   = (float*)(W + 5184);
  float* part    = (float*)(W + 8192);            // 64*2*512 f32
  unsigned short* x_bf = (unsigned short*)(W + 2367488);
  unsigned short* p_bf = (unsigned short*)(W + 6561792);
  unsigned short* y_t  = (unsigned short*)(W + 10756096);   // [2][4096][512]
  unsigned short* act1 = (unsigned short*)(W + 19144704);   // [2][4096][512]
  float* h1_t          = (float*)(W + 27533312);            // [2][4096][256]
  unsigned short* act2 = (unsigned short*)(W + 35921920);   // [2][4096][256]
  unsigned short* w1t  = (unsigned short*)(W + 40116224);   // [9][16][256][32]
  unsigned short* w2t  = (unsigned short*)(W + 42475520);   // [9][8][256][32]
  unsigned short* w3b  = (unsigned short*)(W + 43655168);   // [256][512]
  float* t1      = (float*)(W + 43917312);        // 4608 f32
  float* t2      = (float*)(W + 43935744);        // 2304 f32
  float* t3      = (float*)(W + 43944960);        // 512 f32
  float* invn    = (float*)(W + 43947008);        // 3 f32
  float* st      = (float*)(W + 43947072);        // 768 f32
  // qt parks in act1's region (act1 is written only after energy completes)
  unsigned short* qt = (unsigned short*)(W + 19144704);     // [2][4096][64] bf16

  hipLaunchKernelGGL(snA_kernel, dim3(29), dim3(256), 0, stream,
                     c1w, u1, c2w, u2, byw, u3, t1, t2, t3);
  hipLaunchKernelGGL(snN_kernel, dim3(3), dim3(256), 0, stream, t1, t2, t3, invn);
  hipLaunchKernelGGL(snB_kernel, dim3(192), dim3(256), 0, stream,
                     c1w, t1, c2w, t2, byw, t3, st);
  hipLaunchKernelGGL(snC_kernel, dim3(3), dim3(256), 0, stream, st, invn, inv_sig);
  hipLaunchKernelGGL(cast_xp_kernel, dim3(1024, 2), dim3(256), 0, stream, x, pre, x_bf, p_bf);
  hipLaunchKernelGGL(transpose_w_kernel, dim3(4608), dim3(256), 0, stream, c1w, w1t, 512);
  hipLaunchKernelGGL(transpose_w_kernel, dim3(2304), dim3(256), 0, stream, c2w, w2t, 256);
  hipLaunchKernelGGL(cast_w3_kernel, dim3(64), dim3(256), 0, stream, byw, w3b);
  hipLaunchKernelGGL(qgemm_kernel, dim3(64, 2), dim3(256), 0, stream, x_bf, qw, qt);
  hipLaunchKernelGGL(energy_mfma_kernel, dim3(32, 32, 2), dim3(256), 0, stream, qt, att);
  hipLaunchKernelGGL(softmax_kernel, dim3(8192), dim3(256), 0, stream, att);
  hipLaunchKernelGGL(outcf_mfma_kernel, dim3(512), dim3(256), 0, stream,
                     x_bf, p_bf, x, pre, att, mask, gamma, alpha, y_t);
  hipLaunchKernelGGL(bn_part_kernel, dim3(64), dim3(256), 0, stream,
                     (const void*)y_t, 1, 512, 128, part);
  hipLaunchKernelGGL(bn_finish_kernel, dim3(1), dim3(256), 0, stream,
                     part, 512, 64, 1.0f / 8192.0f, mean1, rstd1);
  hipLaunchKernelGGL(bn_act_bf_kernel, dim3(8192), dim3(256), 0, stream,
                     y_t, act1, mean1, rstd1, bn1s, bn1b, 511);
  hipLaunchKernelGGL(conv3x3_mfma_kernel, dim3(64, 4, 2), dim3(256), 0, stream,
                     act1, w1t, inv_sig, 0, 512, 0, h1_t);
  hipLaunchKernelGGL(bn_part_kernel, dim3(64), dim3(256), 0, stream,
                     (const void*)h1_t, 0, 256, 128, part);
  hipLaunchKernelGGL(bn_finish_kernel, dim3(1), dim3(256), 0, stream,
                     part, 256, 64, 1.0f / 8192.0f, mean2, rstd2);
  hipLaunchKernelGGL(bn_act_f_kernel, dim3(2048), dim3(256), 0, stream,
                     h1_t, act2, mean2, rstd2, bn2s, bn2b, 255);
  hipLaunchKernelGGL(scgemm_mfma_kernel, dim3(64, 4, 2), dim3(256), 0, stream,
                     y_t, w3b, inv_sig, res);
  hipLaunchKernelGGL(conv3x3_mfma_kernel, dim3(64, 4, 2), dim3(256), 0, stream,
                     act2, w2t, inv_sig, 1, 256, 1, res);
}

// Round 7
// 684.809 us; speedup vs baseline: 1.0495x; 1.0495x over previous
//
#include <hip/hip_runtime.h>
#include <cstddef>

// B=2, C=256, W=H=64, N=4096, Cq=64
// outputs: res (2*256*4096) then attention (2*4096*4096), fp32

typedef __attribute__((ext_vector_type(8))) short bh8;   // 8 bf16 (4 VGPR)
typedef __attribute__((ext_vector_type(4))) short bh4;   // 4 bf16 (8B)
typedef __attribute__((ext_vector_type(4))) float f4;    // MFMA acc

static __device__ __forceinline__ short f2bf(float f) {
  unsigned u = __float_as_uint(f);
  unsigned r = (u + 0x7fffu + ((u >> 16) & 1u)) >> 16;
  return (short)r;
}
static __device__ __forceinline__ float bf2f(unsigned short s) {
  return __uint_as_float(((unsigned)s) << 16);
}

__device__ __forceinline__ float blk_sum256(float v, float* sm) {
#pragma unroll
  for (int o = 32; o > 0; o >>= 1) v += __shfl_down(v, o, 64);
  __syncthreads();
  if ((threadIdx.x & 63) == 0) sm[threadIdx.x >> 6] = v;
  __syncthreads();
  return sm[0] + sm[1] + sm[2] + sm[3];
}

__device__ __forceinline__ float blk_max256(float v, float* sm) {
#pragma unroll
  for (int o = 32; o > 0; o >>= 1) v = fmaxf(v, __shfl_down(v, o, 64));
  __syncthreads();
  if ((threadIdx.x & 63) == 0) sm[threadIdx.x >> 6] = v;
  __syncthreads();
  return fmaxf(fmaxf(sm[0], sm[1]), fmaxf(sm[2], sm[3]));
}

// swizzled LDS column (shorts): keeps 16B granules, spreads banks, no pad
#define SWCOL(row, col) ((col) ^ ((((row) >> 1) & 3) << 3))

// ==== spectral norm, parallel: t = W^T u ====
__global__ __launch_bounds__(256) void snA_kernel(
    const float* __restrict__ w1, const float* __restrict__ u1,
    const float* __restrict__ w2, const float* __restrict__ u2,
    const float* __restrict__ w3, const float* __restrict__ u3,
    float* __restrict__ t1, float* __restrict__ t2, float* __restrict__ t3) {
  int g = blockIdx.x * 256 + threadIdx.x;   // 0..7423
  const float* W; const float* u; float* t; int K; int j;
  if (g < 4608)      { W = w1; u = u1; t = t1; K = 4608; j = g; }
  else if (g < 6912) { W = w2; u = u2; t = t2; K = 2304; j = g - 4608; }
  else if (g < 7424) { W = w3; u = u3; t = t3; K = 512;  j = g - 6912; }
  else return;
  float a = 0.f;
  for (int i = 0; i < 256; ++i) a += W[(size_t)i * K + j] * u[i];
  t[j] = a;
}

// ==== invn[w] = 1/(||t||+eps) ====
__global__ __launch_bounds__(256) void snN_kernel(
    const float* __restrict__ t1, const float* __restrict__ t2,
    const float* __restrict__ t3, float* __restrict__ invn) {
  __shared__ float red[4];
  const float* t; int K;
  if (blockIdx.x == 0)      { t = t1; K = 4608; }
  else if (blockIdx.x == 1) { t = t2; K = 2304; }
  else                      { t = t3; K = 512;  }
  float ss = 0.f;
  for (int j = threadIdx.x; j < K; j += 256) { float v = t[j]; ss += v * v; }
  ss = blk_sum256(ss, red);
  if (threadIdx.x == 0) invn[blockIdx.x] = 1.0f / (sqrtf(ss) + 1e-12f);
}

// ==== st = W t (wave per row) ====
__global__ __launch_bounds__(256) void snB_kernel(
    const float* __restrict__ w1, const float* __restrict__ t1,
    const float* __restrict__ w2, const float* __restrict__ t2,
    const float* __restrict__ w3, const float* __restrict__ t3,
    float* __restrict__ st) {
  int blk = blockIdx.x;                // 192 blocks: w*64 + rowgrp
  int w = blk >> 6;
  const float* W; const float* t; int K;
  if (w == 0)      { W = w1; t = t1; K = 4608; }
  else if (w == 1) { W = w2; t = t2; K = 2304; }
  else             { W = w3; t = t3; K = 512;  }
  int lane = threadIdx.x & 63, wave = threadIdx.x >> 6;
  int row = (blk & 63) * 4 + wave;
  const float* Wr = W + (size_t)row * K;
  float a = 0.f;
  for (int j = lane; j < K; j += 64) a += Wr[j] * t[j];
#pragma unroll
  for (int o = 32; o > 0; o >>= 1) a += __shfl_down(a, o, 64);
  if (lane == 0) st[w * 256 + row] = a;
}

// ==== sigma -> inv_sig ====
__global__ __launch_bounds__(256) void snC_kernel(
    const float* __restrict__ st, const float* __restrict__ invn,
    float* __restrict__ inv_sig) {
  __shared__ float red[4];
  int w = blockIdx.x;
  float v = st[w * 256 + threadIdx.x];
  float ss = blk_sum256(v * v, red);
  if (threadIdx.x == 0) {
    float in = invn[w];
    float s2 = in * in * ss;            // ||s||^2
    float sn = in * sqrtf(ss);          // ||s||
    float sigma = s2 / (sn + 1e-12f);
    inv_sig[w] = 1.0f / sigma;
  }
}

// ---- cast x / pre to bf16 (same [c][n] layout) ----
__global__ __launch_bounds__(256) void cast_xp_kernel(
    const float* __restrict__ x, const float* __restrict__ pre,
    unsigned short* __restrict__ xb, unsigned short* __restrict__ pb) {
  int i = blockIdx.x * 256 + threadIdx.x;   // 8 elems per thread
  const float* s = blockIdx.y ? pre : x;
  unsigned short* d = blockIdx.y ? pb : xb;
  float4 v0 = ((const float4*)s)[i * 2];
  float4 v1 = ((const float4*)s)[i * 2 + 1];
  bh8 o = { f2bf(v0.x), f2bf(v0.y), f2bf(v0.z), f2bf(v0.w),
            f2bf(v1.x), f2bf(v1.y), f2bf(v1.z), f2bf(v1.w) };
  *(bh8*)&d[(size_t)i * 8] = o;
}

// ---- conv weights OIHW -> [tap][cichunk][co][ci32], bf16 (coalesced B-op) ----
__global__ __launch_bounds__(256) void transpose_w_kernel(
    const float* __restrict__ src, unsigned short* __restrict__ dst, int Cin) {
  int i = blockIdx.x * 256 + threadIdx.x;   // linear over 9*256*Cin
  int ciin = i & 31;
  int co = (i >> 5) & 255;
  int rest = i >> 13;                       // t*nchunk + cc
  int nchunk = Cin >> 5;
  int cc = rest % nchunk;
  int t = rest / nchunk;
  int ci = (cc << 5) + ciin;
  dst[i] = (unsigned short)f2bf(src[((size_t)co * Cin + ci) * 9 + t]);
}

// ---- cast by_w [256][512] to bf16 ----
__global__ __launch_bounds__(256) void cast_w3_kernel(
    const float* __restrict__ src, unsigned short* __restrict__ dst) {
  int i = blockIdx.x * 256 + threadIdx.x;   // 8 elems per thread
  float4 v0 = ((const float4*)src)[i * 2];
  float4 v1 = ((const float4*)src)[i * 2 + 1];
  bh8 o = { f2bf(v0.x), f2bf(v0.y), f2bf(v0.z), f2bf(v0.w),
            f2bf(v1.x), f2bf(v1.y), f2bf(v1.z), f2bf(v1.w) };
  *(bh8*)&dst[(size_t)i * 8] = o;
}

// ---- fused q = qw*x (1x1 conv) -> qt [n][64] bf16, MFMA ----
// Per block: 64 n-rows, full cq=64, K=256 split 4 waves x 64c (2 chunks).
// A = x^T staged via scalar LDS transpose; B = qw cast inline to bf16.
__global__ __launch_bounds__(256, 2) void qgemm_kernel(
    const unsigned short* __restrict__ xb, const float* __restrict__ qw,
    unsigned short* __restrict__ qt) {
  int b = blockIdx.y;
  int n0 = blockIdx.x * 64;
  __shared__ short smem[24576];      // 48 KB (staging 32 KB; reduce reuse)
  int tid = threadIdx.x;
  int wave = tid >> 6, lane = tid & 63;
  short* Wt = smem + wave * 4096;
  short* Xt = Wt + 2048;
  int ln = lane & 15, qd = lane >> 4;
  int part = lane & 3, r4 = lane >> 2;
  int cl = lane >> 1, ng = lane & 1;
  f4 z = {0.f, 0.f, 0.f, 0.f};
  f4 acc[4][4];
#pragma unroll
  for (int i = 0; i < 4; ++i)
#pragma unroll
    for (int j = 0; j < 4; ++j) acc[i][j] = z;
#pragma unroll
  for (int kc = 0; kc < 2; ++kc) {
    int cc = wave * 2 + kc;
    int c0c = cc << 5;
    // stage weight chunk [cq=64][c=32] bf16 (cast f32 inline)
#pragma unroll
    for (int t2 = 0; t2 < 4; ++t2) {
      int rr = r4 + t2 * 16;
      const float* wp = &qw[rr * 256 + c0c + part * 8];
      float4 v0 = *(const float4*)wp;
      float4 v1 = *(const float4*)(wp + 4);
      bh8 o = { f2bf(v0.x), f2bf(v0.y), f2bf(v0.z), f2bf(v0.w),
                f2bf(v1.x), f2bf(v1.y), f2bf(v1.z), f2bf(v1.w) };
      *(bh8*)&Wt[rr * 32 + SWCOL(rr, part * 8)] = o;
    }
    // stage x^T chunk [n=64][c=32] via scalar transpose (reads coalesced)
#pragma unroll
    for (int it = 0; it < 4; ++it) {
      int gg = ng + it * 2;
      bh8 v = *(const bh8*)&xb[((size_t)(b * 256 + c0c + cl) << 12) + n0 + gg * 8];
#pragma unroll
      for (int e = 0; e < 8; ++e) {
        int nl = gg * 8 + e;
        Xt[nl * 32 + (cl ^ (((nl >> 1) & 3) << 3))] = v[e];
      }
    }
    // wave-synchronous MFMA (same-wave ds_write -> ds_read)
    bh8 bw[4];
#pragma unroll
    for (int j = 0; j < 4; ++j) {
      int row = j * 16 + ln;
      bw[j] = *(const bh8*)&Wt[row * 32 + SWCOL(row, qd * 8)];
    }
#pragma unroll
    for (int i = 0; i < 4; ++i) {
      int row = i * 16 + ln;
      bh8 a = *(const bh8*)&Xt[row * 32 + SWCOL(row, qd * 8)];
#pragma unroll
      for (int j = 0; j < 4; ++j)
        acc[i][j] = __builtin_amdgcn_mfma_f32_16x16x32_bf16(a, bw[j], acc[i][j], 0, 0, 0);
    }
  }
  // cross-wave reduction: wave j owns cq subtile j
  float* red = (float*)smem;
  __syncthreads();
#pragma unroll
  for (int j = 0; j < 4; ++j) {
    if (j == wave) continue;
    int s = wave - (wave > j ? 1 : 0);
#pragma unroll
    for (int i = 0; i < 4; ++i)
      *(f4*)&red[((((j * 3 + s) << 2) + i) << 8) + (lane << 2)] = acc[i][j];
  }
  __syncthreads();
#pragma unroll
  for (int j = 0; j < 4; ++j) {
    if (j != wave) continue;
#pragma unroll
    for (int s = 0; s < 3; ++s)
#pragma unroll
      for (int i = 0; i < 4; ++i) {
        f4 v = *(const f4*)&red[((((j * 3 + s) << 2) + i) << 8) + (lane << 2)];
        acc[i][j][0] += v[0]; acc[i][j][1] += v[1];
        acc[i][j][2] += v[2]; acc[i][j][3] += v[3];
      }
  }
  // epilogue: qt[b][n][cq], wave writes cq subtile == wave
#pragma unroll
  for (int j = 0; j < 4; ++j) {
    if (j != wave) continue;
#pragma unroll
    for (int i = 0; i < 4; ++i) {
      int n = n0 + i * 16 + qd * 4;
#pragma unroll
      for (int r = 0; r < 4; ++r)
        qt[((size_t)(b * 4096 + n + r) << 6) + j * 16 + ln] =
            (unsigned short)f2bf(acc[i][j][r]);
    }
  }
}

// ---- energy via MFMA bf16: 128x128 tile, 4 waves (2x2), K=64 ----
__global__ __launch_bounds__(256, 4) void energy_mfma_kernel(
    const unsigned short* __restrict__ qt, float* __restrict__ att) {
  int b = blockIdx.z;
  int n0 = blockIdx.x << 7;
  int m0 = blockIdx.y << 7;
  __shared__ short Qn[128 * 64];
  __shared__ short Qm[128 * 64];
  int tid = threadIdx.x;
  int wave = tid >> 6, lane = tid & 63;
  int ln = lane & 15, qd = lane >> 4;
  int wy = wave >> 1, wx = wave & 1;
  int g = tid & 7, row0 = tid >> 3;         // 8 granules x 32 rows
#pragma unroll
  for (int it = 0; it < 4; ++it) {
    int r = row0 + it * 32;
    int colb = ((g ^ (r & 7)) << 3);
    *(bh8*)&Qn[(r << 6) + colb] =
        *(const bh8*)&qt[((size_t)(b * 4096 + n0 + r) << 6) + (g << 3)];
    *(bh8*)&Qm[(r << 6) + colb] =
        *(const bh8*)&qt[((size_t)(b * 4096 + m0 + r) << 6) + (g << 3)];
  }
  __syncthreads();
  f4 z = {0.f, 0.f, 0.f, 0.f};
  f4 acc[4][4];
#pragma unroll
  for (int i = 0; i < 4; ++i)
#pragma unroll
    for (int j = 0; j < 4; ++j) acc[i][j] = z;
#pragma unroll
  for (int kc = 0; kc < 2; ++kc) {
    bh8 am[4];
#pragma unroll
    for (int j = 0; j < 4; ++j) {
      int row = wx * 64 + j * 16 + ln;
      int colb = (((qd + (kc << 2)) ^ (row & 7)) << 3);
      am[j] = *(const bh8*)&Qm[(row << 6) + colb];
    }
#pragma unroll
    for (int i = 0; i < 4; ++i) {
      int row = wy * 64 + i * 16 + ln;
      int colb = (((qd + (kc << 2)) ^ (row & 7)) << 3);
      bh8 an = *(const bh8*)&Qn[(row << 6) + colb];
#pragma unroll
      for (int j = 0; j < 4; ++j)
        acc[i][j] = __builtin_amdgcn_mfma_f32_16x16x32_bf16(an, am[j], acc[i][j], 0, 0, 0);
    }
  }
  size_t base = ((size_t)b << 24);
#pragma unroll
  for (int i = 0; i < 4; ++i) {
    int n = n0 + wy * 64 + i * 16 + qd * 4;
#pragma unroll
    for (int j = 0; j < 4; ++j) {
      int m = m0 + wx * 64 + j * 16 + ln;
#pragma unroll
      for (int r = 0; r < 4; ++r)
        att[base + (((size_t)(n + r)) << 12) + m] = acc[i][j][r];
    }
  }
}

// ---- softmax in place over last dim 4096 ----
__global__ __launch_bounds__(256) void softmax_kernel(float* __restrict__ att) {
  __shared__ float red[4];
  size_t row = blockIdx.x;
  float4* rp4 = (float4*)(att + (row << 12));
  int tid = threadIdx.x;
  float4 v[4];
#pragma unroll
  for (int i = 0; i < 4; ++i) v[i] = rp4[tid + (i << 8)];
  float mx = -INFINITY;
#pragma unroll
  for (int i = 0; i < 4; ++i)
    mx = fmaxf(mx, fmaxf(fmaxf(v[i].x, v[i].y), fmaxf(v[i].z, v[i].w)));
  mx = blk_max256(mx, red);
  float s = 0.f;
#pragma unroll
  for (int i = 0; i < 4; ++i) {
    v[i].x = __expf(v[i].x - mx); v[i].y = __expf(v[i].y - mx);
    v[i].z = __expf(v[i].z - mx); v[i].w = __expf(v[i].w - mx);
    s += v[i].x + v[i].y + v[i].z + v[i].w;
  }
  s = blk_sum256(s, red);
  float inv = 1.0f / s;
#pragma unroll
  for (int i = 0; i < 4; ++i) {
    v[i].x *= inv; v[i].y *= inv; v[i].z *= inv; v[i].w *= inv;
    rp4[tid + (i << 8)] = v[i];
  }
}

// ---- fused out/cf MFMA GEMM: 4 waves, k-split, 2-deep bf16 att prefetch ----
// 2-D grid (64,4,2): linear bid = j0 + 64*c0grp + 256*b, so the 4 blocks
// sharing each att row differ by 64 ≡ 0 (mod 8) -> SAME XCD L2 (measured:
// r4 FETCH ~110MB). r6's bid&7=(b,c0) decode put them on 4 different XCDs
// -> att replicated 3-4x (FETCH 392MB) + partial-line y_t writes (40MB).
__global__ __launch_bounds__(256, 2) void outcf_mfma_kernel(
    const unsigned short* __restrict__ xb, const unsigned short* __restrict__ pb,
    const float* __restrict__ x, const float* __restrict__ pre,
    const float* __restrict__ att, const float* __restrict__ mask,
    const float* __restrict__ gamma_p, const float* __restrict__ alpha_p,
    unsigned short* __restrict__ y_t) {
  int b = blockIdx.z;
  int c0 = blockIdx.y * 64;
  int j0 = blockIdx.x * 64;
  __shared__ short smem[12 * 64 * 32];   // 49152 B: 4 waves x (Xs,Ps,As) 64x32
  int tid = threadIdx.x;
  int wave = tid >> 6, lane = tid & 63;
  short* Xs = smem + wave * (3 * 2048);
  short* Ps = Xs + 2048;
  short* As = Ps + 2048;
  int ln = lane & 15, qd = lane >> 4;
  f4 z = {0.f, 0.f, 0.f, 0.f};
  f4 accO[4][4], accC[4][4];
#pragma unroll
  for (int i = 0; i < 4; ++i)
#pragma unroll
    for (int j = 0; j < 4; ++j) { accO[i][j] = z; accC[i][j] = z; }
  int part = lane & 3, r4 = lane >> 2;
  int part8 = lane & 7, r8 = lane >> 3;
  int kb = wave << 10;                       // 1024 k per wave
  size_t abase = ((size_t)b << 24);
  bh8 xr[4], pr[4];
  bh4 arA[8], arB[8];                        // 2-deep att prefetch, bf16
  // prologue: xr/pr @kb, arA @kb, arB @kb+32
#pragma unroll
  for (int t2 = 0; t2 < 4; ++t2) {
    int rr = r4 + t2 * 16;
    xr[t2] = *(const bh8*)&xb[((size_t)(b * 256 + c0 + rr) << 12) + kb + part * 8];
    pr[t2] = *(const bh8*)&pb[((size_t)(b * 256 + c0 + rr) << 12) + kb + part * 8];
  }
#pragma unroll
  for (int t2 = 0; t2 < 8; ++t2) {
    int rr = r8 + t2 * 8;
    float4 v = *(const float4*)&att[abase + ((size_t)(j0 + rr) << 12) + kb + part8 * 4];
    bh4 o = { f2bf(v.x), f2bf(v.y), f2bf(v.z), f2bf(v.w) };
    arA[t2] = o;
  }
#pragma unroll
  for (int t2 = 0; t2 < 8; ++t2) {
    int rr = r8 + t2 * 8;
    float4 v = *(const float4*)&att[abase + ((size_t)(j0 + rr) << 12) + kb + 32 + part8 * 4];
    bh4 o = { f2bf(v.x), f2bf(v.y), f2bf(v.z), f2bf(v.w) };
    arB[t2] = o;
  }
  for (int it = 0; it < 32; it += 2) {
    int kA = kb + (it << 5);
    // ---- phase A (k = kA, data in xr/pr/arA) ----
#pragma unroll
    for (int t2 = 0; t2 < 4; ++t2) {
      int rr = r4 + t2 * 16;
      int col = SWCOL(rr, part * 8);
      *(bh8*)&Xs[rr * 32 + col] = xr[t2];
      *(bh8*)&Ps[rr * 32 + col] = pr[t2];
    }
#pragma unroll
    for (int t2 = 0; t2 < 8; ++t2) {
      int rr = r8 + t2 * 8;
      *(bh4*)&As[rr * 32 + SWCOL(rr, part8 * 4)] = arA[t2];
    }
    {
      int k1 = kA + 32;
#pragma unroll
      for (int t2 = 0; t2 < 4; ++t2) {
        int rr = r4 + t2 * 16;
        xr[t2] = *(const bh8*)&xb[((size_t)(b * 256 + c0 + rr) << 12) + k1 + part * 8];
        pr[t2] = *(const bh8*)&pb[((size_t)(b * 256 + c0 + rr) << 12) + k1 + part * 8];
      }
    }
    if (it + 2 < 32) {
      int k2 = kA + 64;
#pragma unroll
      for (int t2 = 0; t2 < 8; ++t2) {
        int rr = r8 + t2 * 8;
        float4 v = *(const float4*)&att[abase + ((size_t)(j0 + rr) << 12) + k2 + part8 * 4];
        bh4 o = { f2bf(v.x), f2bf(v.y), f2bf(v.z), f2bf(v.w) };
        arA[t2] = o;
      }
    }
    {
      bh8 bf[4];
#pragma unroll
      for (int j = 0; j < 4; ++j) {
        int row = j * 16 + ln;
        bf[j] = *(const bh8*)&As[row * 32 + SWCOL(row, qd * 8)];
      }
#pragma unroll
      for (int i = 0; i < 4; ++i) {
        int row = i * 16 + ln;
        int col = SWCOL(row, qd * 8);
        bh8 ax = *(const bh8*)&Xs[row * 32 + col];
        bh8 ap = *(const bh8*)&Ps[row * 32 + col];
#pragma unroll
        for (int j = 0; j < 4; ++j) {
          accO[i][j] = __builtin_amdgcn_mfma_f32_16x16x32_bf16(ax, bf[j], accO[i][j], 0, 0, 0);
          accC[i][j] = __builtin_amdgcn_mfma_f32_16x16x32_bf16(ap, bf[j], accC[i][j], 0, 0, 0);
        }
      }
    }
    // ---- phase B (k = kA+32, data in xr/pr/arB) ----
    int kB = kA + 32;
#pragma unroll
    for (int t2 = 0; t2 < 4; ++t2) {
      int rr = r4 + t2 * 16;
      int col = SWCOL(rr, part * 8);
      *(bh8*)&Xs[rr * 32 + col] = xr[t2];
      *(bh8*)&Ps[rr * 32 + col] = pr[t2];
    }
#pragma unroll
    for (int t2 = 0; t2 < 8; ++t2) {
      int rr = r8 + t2 * 8;
      *(bh4*)&As[rr * 32 + SWCOL(rr, part8 * 4)] = arB[t2];
    }
    if (it + 2 < 32) {
      int k1 = kB + 32;
#pragma unroll
      for (int t2 = 0; t2 < 4; ++t2) {
        int rr = r4 + t2 * 16;
        xr[t2] = *(const bh8*)&xb[((size_t)(b * 256 + c0 + rr) << 12) + k1 + part * 8];
        pr[t2] = *(const bh8*)&pb[((size_t)(b * 256 + c0 + rr) << 12) + k1 + part * 8];
      }
    }
    if (it + 3 < 32) {
      int k2 = kB + 64;
#pragma unroll
      for (int t2 = 0; t2 < 8; ++t2) {
        int rr = r8 + t2 * 8;
        float4 v = *(const float4*)&att[abase + ((size_t)(j0 + rr) << 12) + k2 + part8 * 4];
        bh4 o = { f2bf(v.x), f2bf(v.y), f2bf(v.z), f2bf(v.w) };
        arB[t2] = o;
      }
    }
    {
      bh8 bf[4];
#pragma unroll
      for (int j = 0; j < 4; ++j) {
        int row = j * 16 + ln;
        bf[j] = *(const bh8*)&As[row * 32 + SWCOL(row, qd * 8)];
      }
#pragma unroll
      for (int i = 0; i < 4; ++i) {
        int row = i * 16 + ln;
        int col = SWCOL(row, qd * 8);
        bh8 ax = *(const bh8*)&Xs[row * 32 + col];
        bh8 ap = *(const bh8*)&Ps[row * 32 + col];
#pragma unroll
        for (int j = 0; j < 4; ++j) {
          accO[i][j] = __builtin_amdgcn_mfma_f32_16x16x32_bf16(ax, bf[j], accO[i][j], 0, 0, 0);
          accC[i][j] = __builtin_amdgcn_mfma_f32_16x16x32_bf16(ap, bf[j], accC[i][j], 0, 0, 0);
        }
      }
    }
  }
  // ---- cross-wave k-reduction: wave j owns column block j ----
  float* red = (float*)smem;
  __syncthreads();
#pragma unroll
  for (int j = 0; j < 4; ++j) {
    if (j == wave) continue;
    int s = wave - (wave > j ? 1 : 0);
#pragma unroll
    for (int i = 0; i < 4; ++i)
      *(f4*)&red[((((j * 3 + s) << 2) + i) << 8) + (lane << 2)] = accO[i][j];
  }
  __syncthreads();
#pragma unroll
  for (int j = 0; j < 4; ++j) {
    if (j != wave) continue;
#pragma unroll
    for (int s = 0; s < 3; ++s)
#pragma unroll
      for (int i = 0; i < 4; ++i) {
        f4 v = *(const f4*)&red[((((j * 3 + s) << 2) + i) << 8) + (lane << 2)];
        accO[i][j][0] += v[0]; accO[i][j][1] += v[1];
        accO[i][j][2] += v[2]; accO[i][j][3] += v[3];
      }
  }
  __syncthreads();
#pragma unroll
  for (int j = 0; j < 4; ++j) {
    if (j == wave) continue;
    int s = wave - (wave > j ? 1 : 0);
#pragma unroll
    for (int i = 0; i < 4; ++i)
      *(f4*)&red[((((j * 3 + s) << 2) + i) << 8) + (lane << 2)] = accC[i][j];
  }
  __syncthreads();
#pragma unroll
  for (int j = 0; j < 4; ++j) {
    if (j != wave) continue;
#pragma unroll
    for (int s = 0; s < 3; ++s)
#pragma unroll
      for (int i = 0; i < 4; ++i) {
        f4 v = *(const f4*)&red[((((j * 3 + s) << 2) + i) << 8) + (lane << 2)];
        accC[i][j][0] += v[0]; accC[i][j][1] += v[1];
        accC[i][j][2] += v[2]; accC[i][j][3] += v[3];
      }
  }
  // ---- epilogue: wave handles j == wave ----
  float g = gamma_p[0], al = alpha_p[0];
#pragma unroll
  for (int j = 0; j < 4; ++j) {
    if (j != wave) continue;
    int jp = j0 + j * 16 + ln;
    float mv = mask[(b << 12) + jp];
#pragma unroll
    for (int i = 0; i < 4; ++i) {
      int cb = c0 + i * 16 + qd * 4;
      bh4 oY, oC;
#pragma unroll
      for (int r = 0; r < 4; ++r) {
        float xo = x[((size_t)(b * 256 + cb + r) << 12) + jp];
        float po = pre[((size_t)(b * 256 + cb + r) << 12) + jp];
        oY[r] = f2bf(g * accO[i][j][r] + xo);
        oC[r] = f2bf(al * (1.f - mv) * accC[i][j][r] + mv * po);
      }
      size_t rowb = ((size_t)b * 4096 + jp) * 512;
      *(bh4*)&y_t[rowb + cb] = oY;
      *(bh4*)&y_t[rowb + 256 + cb] = oC;
    }
  }
}

// ---- BN stats phase 1 ----
__global__ __launch_bounds__(256) void bn_part_kernel(
    const void* __restrict__ src, int isbf, int C, int rows_per_slab,
    float* __restrict__ part) {
  int slab = blockIdx.x;
  int r0 = slab * rows_per_slab;
  for (int co = threadIdx.x; co < C; co += 256) {
    float s = 0.f, ss = 0.f;
    if (isbf) {
      const unsigned short* p = (const unsigned short*)src;
      for (int r = 0; r < rows_per_slab; ++r) {
        float v = bf2f(p[(size_t)(r0 + r) * C + co]); s += v; ss += v * v;
      }
    } else {
      const float* p = (const float*)src;
      for (int r = 0; r < rows_per_slab; ++r) {
        float v = p[(size_t)(r0 + r) * C + co]; s += v; ss += v * v;
      }
    }
    part[(size_t)(slab * 2) * C + co] = s;
    part[(size_t)(slab * 2 + 1) * C + co] = ss;
  }
}

// ---- BN stats phase 2 ----
__global__ __launch_bounds__(256) void bn_finish_kernel(
    const float* __restrict__ part, int C, int slabs, float inv_count,
    float* __restrict__ mean, float* __restrict__ rstd) {
  for (int co = threadIdx.x; co < C; co += 256) {
    float s = 0.f, ss = 0.f;
    for (int sl = 0; sl < slabs; ++sl) {
      s += part[(size_t)(sl * 2) * C + co];
      ss += part[(size_t)(sl * 2 + 1) * C + co];
    }
    float m = s * inv_count;
    float var = ss * inv_count - m * m;
    mean[co] = m;
    rstd[co] = rsqrtf(var + 1e-5f);
  }
}

// ---- BN apply + leaky, bf16 -> bf16 ([n][C] layout) ----
__global__ __launch_bounds__(256) void bn_act_bf_kernel(
    const unsigned short* __restrict__ src, unsigned short* __restrict__ dst,
    const float* __restrict__ mean, const float* __restrict__ rstd,
    const float* __restrict__ sc, const float* __restrict__ bi, int Cm1) {
  int i = blockIdx.x * 256 + threadIdx.x;   // 4 elems
  int ch = (i * 4) & Cm1;
  bh4 v = *(const bh4*)&src[(size_t)i * 4];
  bh4 o;
#pragma unroll
  for (int e = 0; e < 4; ++e) {
    int c = ch + e;
    float a = rstd[c] * sc[c];
    float bb = bi[c] - mean[c] * a;
    float f = bf2f((unsigned short)v[e]) * a + bb;
    f = f > 0.f ? f : 0.01f * f;
    o[e] = f2bf(f);
  }
  *(bh4*)&dst[(size_t)i * 4] = o;
}

// ---- BN apply + leaky, f32 -> bf16 ----
__global__ __launch_bounds__(256) void bn_act_f_kernel(
    const float* __restrict__ src, unsigned short* __restrict__ dst,
    const float* __restrict__ mean, const float* __restrict__ rstd,
    const float* __restrict__ sc, const float* __restrict__ bi, int Cm1) {
  int i = blockIdx.x * 256 + threadIdx.x;   // 4 elems
  int ch = (i * 4) & Cm1;
  float4 v = ((const float4*)src)[i];
  float vv[4] = {v.x, v.y, v.z, v.w};
  bh4 o;
#pragma unroll
  for (int e = 0; e < 4; ++e) {
    int c = ch + e;
    float a = rstd[c] * sc[c];
    float bb = bi[c] - mean[c] * a;
    float f = vv[e] * a + bb;
    f = f > 0.f ? f : 0.01f * f;
    o[e] = f2bf(f);
  }
  *(bh4*)&dst[(size_t)i * 4] = o;
}

// ---- 3x3 conv: 9 accumulated MFMA GEMMs, 4 waves k-split, T14 prefetch ----
__global__ __launch_bounds__(256, 2) void conv3x3_mfma_kernel(
    const unsigned short* __restrict__ act_t, const unsigned short* __restrict__ wt,
    const float* __restrict__ inv_sig, int sidx, int Cin, int mode,
    float* __restrict__ out) {
  int b = blockIdx.z;
  int co0 = blockIdx.y * 64;
  int n0 = blockIdx.x * 64;
  __shared__ short smem[4 * 194 * 32];   // 49664 B, per-wave act tiles
  int tid = threadIdx.x;
  int wave = tid >> 6, lane = tid & 63;
  short* act_s = smem + wave * (194 * 32);
  int ln = lane & 15, qd = lane >> 4;
  int part = lane & 3, r4 = lane >> 2;
  f4 z = {0.f, 0.f, 0.f, 0.f};
  f4 acc[4][4];
#pragma unroll
  for (int i = 0; i < 4; ++i)
#pragma unroll
    for (int j = 0; j < 4; ++j) acc[i][j] = z;
  bh8 zf = {};
  int nchunk = Cin >> 5;
  int per = nchunk >> 2;                 // chunks per wave
  size_t tstride = (size_t)nchunk * 256 * 32;   // weight tap stride
  int cc0 = wave * per;
  bh8 sreg[13];
  // prologue: prefetch chunk cc0 act into regs
#pragma unroll
  for (int it = 0; it < 13; ++it) {
    int rr = r4 + it * 16;
    bh8 v = {};
    if (rr < 194) {
      int flat = n0 - 65 + rr;
      if ((unsigned)flat < 4096u)
        v = *(const bh8*)&act_t[((size_t)(b * 4096 + flat)) * Cin + (cc0 << 5) + part * 8];
    }
    sreg[it] = v;
  }
  for (int itc = 0; itc < per; ++itc) {
    int cc = cc0 + itc;
    // write staged act to LDS (wave-synchronous, no barrier)
#pragma unroll
    for (int it = 0; it < 13; ++it) {
      int rr = r4 + it * 16;
      if (rr < 194)
        *(bh8*)&act_s[rr * 32 + SWCOL(rr, part * 8)] = sreg[it];
    }
    // issue next chunk's act loads (hidden under the 9-tap MFMA loop)
    if (itc + 1 < per) {
      int ci0n = (cc + 1) << 5;
#pragma unroll
      for (int it = 0; it < 13; ++it) {
        int rr = r4 + it * 16;
        bh8 v = {};
        if (rr < 194) {
          int flat = n0 - 65 + rr;
          if ((unsigned)flat < 4096u)
            v = *(const bh8*)&act_t[((size_t)(b * 4096 + flat)) * Cin + ci0n + part * 8];
        }
        sreg[it] = v;
      }
    }
    // weights: [t][cc][co][ci32] layout, contiguous per (t,cc,j)
    const unsigned short* wb0 = wt + ((size_t)cc * 256) * 32;
    bh8 bwc[4], bwn[4];
#pragma unroll
    for (int j = 0; j < 4; ++j)
      bwc[j] = *(const bh8*)&wb0[(size_t)(co0 + j * 16 + ln) * 32 + qd * 8];
#pragma unroll
    for (int t = 0; t < 9; ++t) {
      if (t < 8) {
        const unsigned short* wbn = wb0 + (size_t)(t + 1) * tstride;
#pragma unroll
        for (int j = 0; j < 4; ++j)
          bwn[j] = *(const bh8*)&wbn[(size_t)(co0 + j * 16 + ln) * 32 + qd * 8];
      }
      int dy = t / 3, dx = t - dy * 3;
      int off = (dy - 1) * 64 + (dx - 1);
#pragma unroll
      for (int i = 0; i < 4; ++i) {
        int px = i * 16 + ln;
        int row = 65 + off + px;
        bh8 a = *(const bh8*)&act_s[row * 32 + SWCOL(row, qd * 8)];
        if (dx == 0 && px == 0) a = zf;
        if (dx == 2 && px == 63) a = zf;
#pragma unroll
        for (int j = 0; j < 4; ++j)
          acc[i][j] = __builtin_amdgcn_mfma_f32_16x16x32_bf16(a, bwc[j], acc[i][j], 0, 0, 0);
      }
      if (t < 8) {
#pragma unroll
        for (int j = 0; j < 4; ++j) bwc[j] = bwn[j];
      }
    }
  }
  // ---- cross-wave reduction: wave j owns column block j ----
  float* red = (float*)smem;
  __syncthreads();
#pragma unroll
  for (int j = 0; j < 4; ++j) {
    if (j == wave) continue;
    int s = wave - (wave > j ? 1 : 0);
#pragma unroll
    for (int i = 0; i < 4; ++i)
      *(f4*)&red[((((j * 3 + s) << 2) + i) << 8) + (lane << 2)] = acc[i][j];
  }
  __syncthreads();
#pragma unroll
  for (int j = 0; j < 4; ++j) {
    if (j != wave) continue;
#pragma unroll
    for (int s = 0; s < 3; ++s)
#pragma unroll
      for (int i = 0; i < 4; ++i) {
        f4 v = *(const f4*)&red[((((j * 3 + s) << 2) + i) << 8) + (lane << 2)];
        acc[i][j][0] += v[0]; acc[i][j][1] += v[1];
        acc[i][j][2] += v[2]; acc[i][j][3] += v[3];
      }
  }
  float isg = inv_sig[sidx];
  if (mode == 0) {
#pragma unroll
    for (int j = 0; j < 4; ++j) {
      if (j != wave) continue;
      int co = co0 + j * 16 + ln;
#pragma unroll
      for (int i = 0; i < 4; ++i) {
        int pb = n0 + i * 16 + qd * 4;
#pragma unroll
        for (int r = 0; r < 4; ++r)
          out[((size_t)(b * 4096 + pb + r)) * 256 + co] = acc[i][j][r] * isg;
      }
    }
  } else {
#pragma unroll
    for (int j = 0; j < 4; ++j) {
      if (j != wave) continue;
      int co = co0 + j * 16 + ln;
#pragma unroll
      for (int i = 0; i < 4; ++i) {
        int pb = n0 + i * 16 + qd * 4;
        float4* rp = (float4*)&out[((size_t)(b * 256 + co) << 12) + pb];
        float4 v = *rp;
        v.x += acc[i][j][0] * isg; v.y += acc[i][j][1] * isg;
        v.z += acc[i][j][2] * isg; v.w += acc[i][j][3] * isg;
        *rp = v;
      }
    }
  }
}

// ---- shortcut 1x1, 4 waves split K=512, T14 prefetch ----
__global__ __launch_bounds__(256, 2) void scgemm_mfma_kernel(
    const unsigned short* __restrict__ y_t, const unsigned short* __restrict__ w3b,
    const float* __restrict__ inv_sig, float* __restrict__ res) {
  int b = blockIdx.z;
  int co0 = blockIdx.y * 64;
  int n0 = blockIdx.x * 64;
  __shared__ short smem[24576];          // 49152 B (staging uses first 16 KB)
  int tid = threadIdx.x;
  int wave = tid >> 6, lane = tid & 63;
  short* Ys = smem + wave * 2048;
  int ln = lane & 15, qd = lane >> 4;
  int part = lane & 3, r4 = lane >> 2;
  f4 z = {0.f, 0.f, 0.f, 0.f};
  f4 acc[4][4];
#pragma unroll
  for (int i = 0; i < 4; ++i)
#pragma unroll
    for (int j = 0; j < 4; ++j) acc[i][j] = z;
  int kb = wave << 7;                    // 128 k per wave
  bh8 ys[4], bwc[4], yn[4], bwn[4];
#pragma unroll
  for (int t2 = 0; t2 < 4; ++t2) {
    int rr = r4 + t2 * 16;
    ys[t2] = *(const bh8*)&y_t[((size_t)(b * 4096 + n0 + rr)) * 512 + kb + part * 8];
  }
#pragma unroll
  for (int j = 0; j < 4; ++j)
    bwc[j] = *(const bh8*)&w3b[((size_t)(co0 + j * 16 + ln)) * 512 + kb + qd * 8];
#pragma unroll
  for (int it = 0; it < 4; ++it) {
    int k0 = kb + (it << 5);
#pragma unroll
    for (int t2 = 0; t2 < 4; ++t2) {
      int rr = r4 + t2 * 16;
      *(bh8*)&Ys[rr * 32 + SWCOL(rr, part * 8)] = ys[t2];
    }
    if (it < 3) {
      int k1 = k0 + 32;
#pragma unroll
      for (int t2 = 0; t2 < 4; ++t2) {
        int rr = r4 + t2 * 16;
        yn[t2] = *(const bh8*)&y_t[((size_t)(b * 4096 + n0 + rr)) * 512 + k1 + part * 8];
      }
#pragma unroll
      for (int j = 0; j < 4; ++j)
        bwn[j] = *(const bh8*)&w3b[((size_t)(co0 + j * 16 + ln)) * 512 + k1 + qd * 8];
    }
#pragma unroll
    for (int i = 0; i < 4; ++i) {
      int row = i * 16 + ln;
      bh8 a = *(const bh8*)&Ys[row * 32 + SWCOL(row, qd * 8)];
#pragma unroll
      for (int j = 0; j < 4; ++j)
        acc[i][j] = __builtin_amdgcn_mfma_f32_16x16x32_bf16(a, bwc[j], acc[i][j], 0, 0, 0);
    }
    if (it < 3) {
#pragma unroll
      for (int t2 = 0; t2 < 4; ++t2) ys[t2] = yn[t2];
#pragma unroll
      for (int j = 0; j < 4; ++j) bwc[j] = bwn[j];
    }
  }
  // ---- cross-wave reduction: wave j owns column block j ----
  float* red = (float*)smem;
  __syncthreads();
#pragma unroll
  for (int j = 0; j < 4; ++j) {
    if (j == wave) continue;
    int s = wave - (wave > j ? 1 : 0);
#pragma unroll
    for (int i = 0; i < 4; ++i)
      *(f4*)&red[((((j * 3 + s) << 2) + i) << 8) + (lane << 2)] = acc[i][j];
  }
  __syncthreads();
#pragma unroll
  for (int j = 0; j < 4; ++j) {
    if (j != wave) continue;
#pragma unroll
    for (int s = 0; s < 3; ++s)
#pragma unroll
      for (int i = 0; i < 4; ++i) {
        f4 v = *(const f4*)&red[((((j * 3 + s) << 2) + i) << 8) + (lane << 2)];
        acc[i][j][0] += v[0]; acc[i][j][1] += v[1];
        acc[i][j][2] += v[2]; acc[i][j][3] += v[3];
      }
  }
  float isg = inv_sig[2];
#pragma unroll
  for (int j = 0; j < 4; ++j) {
    if (j != wave) continue;
    int co = co0 + j * 16 + ln;
#pragma unroll
    for (int i = 0; i < 4; ++i) {
      int pb = n0 + i * 16 + qd * 4;
      float4 o;
      o.x = acc[i][j][0] * isg; o.y = acc[i][j][1] * isg;
      o.z = acc[i][j][2] * isg; o.w = acc[i][j][3] * isg;
      *(float4*)&res[((size_t)(b * 256 + co) << 12) + pb] = o;
    }
  }
}

extern "C" void kernel_launch(void* const* d_in, const int* in_sizes, int n_in,
                              void* d_out, int out_size, void* d_ws, size_t ws_size,
                              hipStream_t stream) {
  const float* x     = (const float*)d_in[0];
  const float* pre   = (const float*)d_in[1];
  const float* mask  = (const float*)d_in[2];
  const float* qw    = (const float*)d_in[3];
  const float* gamma = (const float*)d_in[4];
  const float* alpha = (const float*)d_in[5];
  const float* bn1s  = (const float*)d_in[6];
  const float* bn1b  = (const float*)d_in[7];
  const float* c1w   = (const float*)d_in[8];
  const float* u1    = (const float*)d_in[9];
  const float* bn2s  = (const float*)d_in[11];
  const float* bn2b  = (const float*)d_in[12];
  const float* c2w   = (const float*)d_in[13];
  const float* u2    = (const float*)d_in[14];
  const float* byw   = (const float*)d_in[16];
  const float* u3    = (const float*)d_in[17];

  float* res = (float*)d_out;                 // 2*256*4096
  float* att = res + (size_t)2 * 256 * 4096;  // 2*4096*4096

  char* W = (char*)d_ws;
  float* inv_sig = (float*)(W + 0);
  float* mean1   = (float*)(W + 64);
  float* rstd1   = (float*)(W + 2112);
  float* mean2   = (float*)(W + 4160);
  float* rstd2   = (float*)(W + 5184);
  float* part    = (float*)(W + 8192);            // 64*2*512 f32
  unsigned short* x_bf = (unsigned short*)(W + 2367488);
  unsigned short* p_bf = (unsigned short*)(W + 6561792);
  unsigned short* y_t  = (unsigned short*)(W + 10756096);   // [2][4096][512]
  unsigned short* act1 = (unsigned short*)(W + 19144704);   // [2][4096][512]
  float* h1_t          = (float*)(W + 27533312);            // [2][4096][256]
  unsigned short* act2 = (unsigned short*)(W + 35921920);   // [2][4096][256]
  unsigned short* w1t  = (unsigned short*)(W + 40116224);   // [9][16][256][32]
  unsigned short* w2t  = (unsigned short*)(W + 42475520);   // [9][8][256][32]
  unsigned short* w3b  = (unsigned short*)(W + 43655168);   // [256][512]
  float* t1      = (float*)(W + 43917312);        // 4608 f32
  float* t2      = (float*)(W + 43935744);        // 2304 f32
  float* t3      = (float*)(W + 43944960);        // 512 f32
  float* invn    = (float*)(W + 43947008);        // 3 f32
  float* st      = (float*)(W + 43947072);        // 768 f32
  // qt parks in act1's region (act1 is written only after energy completes)
  unsigned short* qt = (unsigned short*)(W + 19144704);     // [2][4096][64] bf16

  hipLaunchKernelGGL(snA_kernel, dim3(29), dim3(256), 0, stream,
                     c1w, u1, c2w, u2, byw, u3, t1, t2, t3);
  hipLaunchKernelGGL(snN_kernel, dim3(3), dim3(256), 0, stream, t1, t2, t3, invn);
  hipLaunchKernelGGL(snB_kernel, dim3(192), dim3(256), 0, stream,
                     c1w, t1, c2w, t2, byw, t3, st);
  hipLaunchKernelGGL(snC_kernel, dim3(3), dim3(256), 0, stream, st, invn, inv_sig);
  hipLaunchKernelGGL(cast_xp_kernel, dim3(1024, 2), dim3(256), 0, stream, x, pre, x_bf, p_bf);
  hipLaunchKernelGGL(transpose_w_kernel, dim3(4608), dim3(256), 0, stream, c1w, w1t, 512);
  hipLaunchKernelGGL(transpose_w_kernel, dim3(2304), dim3(256), 0, stream, c2w, w2t, 256);
  hipLaunchKernelGGL(cast_w3_kernel, dim3(64), dim3(256), 0, stream, byw, w3b);
  hipLaunchKernelGGL(qgemm_kernel, dim3(64, 2), dim3(256), 0, stream, x_bf, qw, qt);
  hipLaunchKernelGGL(energy_mfma_kernel, dim3(32, 32, 2), dim3(256), 0, stream, qt, att);
  hipLaunchKernelGGL(softmax_kernel, dim3(8192), dim3(256), 0, stream, att);
  hipLaunchKernelGGL(outcf_mfma_kernel, dim3(64, 4, 2), dim3(256), 0, stream,
                     x_bf, p_bf, x, pre, att, mask, gamma, alpha, y_t);
  hipLaunchKernelGGL(bn_part_kernel, dim3(64), dim3(256), 0, stream,
                     (const void*)y_t, 1, 512, 128, part);
  hipLaunchKernelGGL(bn_finish_kernel, dim3(1), dim3(256), 0, stream,
                     part, 512, 64, 1.0f / 8192.0f, mean1, rstd1);
  hipLaunchKernelGGL(bn_act_bf_kernel, dim3(8192), dim3(256), 0, stream,
                     y_t, act1, mean1, rstd1, bn1s, bn1b, 511);
  hipLaunchKernelGGL(conv3x3_mfma_kernel, dim3(64, 4, 2), dim3(256), 0, stream,
                     act1, w1t, inv_sig, 0, 512, 0, h1_t);
  hipLaunchKernelGGL(bn_part_kernel, dim3(64), dim3(256), 0, stream,
                     (const void*)h1_t, 0, 256, 128, part);
  hipLaunchKernelGGL(bn_finish_kernel, dim3(1), dim3(256), 0, stream,
                     part, 256, 64, 1.0f / 8192.0f, mean2, rstd2);
  hipLaunchKernelGGL(bn_act_f_kernel, dim3(2048), dim3(256), 0, stream,
                     h1_t, act2, mean2, rstd2, bn2s, bn2b, 255);
  hipLaunchKernelGGL(scgemm_mfma_kernel, dim3(64, 4, 2), dim3(256), 0, stream,
                     y_t, w3b, inv_sig, res);
  hipLaunchKernelGGL(conv3x3_mfma_kernel, dim3(64, 4, 2), dim3(256), 0, stream,
                     act2, w2t, inv_sig, 1, 256, 1, res);
}

// Round 8
// 585.633 us; speedup vs baseline: 1.2272x; 1.1693x over previous
//
#include <hip/hip_runtime.h>
#include <cstddef>

// B=2, C=256, W=H=64, N=4096, Cq=64
// outputs: res (2*256*4096) then attention (2*4096*4096), fp32

typedef __attribute__((ext_vector_type(8))) short bh8;   // 8 bf16 (4 VGPR)
typedef __attribute__((ext_vector_type(4))) short bh4;   // 4 bf16 (8B)
typedef __attribute__((ext_vector_type(4))) float f4;    // MFMA acc

static __device__ __forceinline__ short f2bf(float f) {
  unsigned u = __float_as_uint(f);
  unsigned r = (u + 0x7fffu + ((u >> 16) & 1u)) >> 16;
  return (short)r;
}
static __device__ __forceinline__ float bf2f(unsigned short s) {
  return __uint_as_float(((unsigned)s) << 16);
}

__device__ __forceinline__ float blk_sum256(float v, float* sm) {
#pragma unroll
  for (int o = 32; o > 0; o >>= 1) v += __shfl_down(v, o, 64);
  __syncthreads();
  if ((threadIdx.x & 63) == 0) sm[threadIdx.x >> 6] = v;
  __syncthreads();
  return sm[0] + sm[1] + sm[2] + sm[3];
}

__device__ __forceinline__ float blk_max256(float v, float* sm) {
#pragma unroll
  for (int o = 32; o > 0; o >>= 1) v = fmaxf(v, __shfl_down(v, o, 64));
  __syncthreads();
  if ((threadIdx.x & 63) == 0) sm[threadIdx.x >> 6] = v;
  __syncthreads();
  return fmaxf(fmaxf(sm[0], sm[1]), fmaxf(sm[2], sm[3]));
}

// swizzled LDS column (shorts): keeps 16B granules, spreads banks, no pad
#define SWCOL(row, col) ((col) ^ ((((row) >> 1) & 3) << 3))

// ==== spectral norm, parallel: t = W^T u ====
__global__ __launch_bounds__(256) void snA_kernel(
    const float* __restrict__ w1, const float* __restrict__ u1,
    const float* __restrict__ w2, const float* __restrict__ u2,
    const float* __restrict__ w3, const float* __restrict__ u3,
    float* __restrict__ t1, float* __restrict__ t2, float* __restrict__ t3) {
  int g = blockIdx.x * 256 + threadIdx.x;   // 0..7423
  const float* W; const float* u; float* t; int K; int j;
  if (g < 4608)      { W = w1; u = u1; t = t1; K = 4608; j = g; }
  else if (g < 6912) { W = w2; u = u2; t = t2; K = 2304; j = g - 4608; }
  else if (g < 7424) { W = w3; u = u3; t = t3; K = 512;  j = g - 6912; }
  else return;
  float a = 0.f;
  for (int i = 0; i < 256; ++i) a += W[(size_t)i * K + j] * u[i];
  t[j] = a;
}

// ==== invn[w] = 1/(||t||+eps) ====
__global__ __launch_bounds__(256) void snN_kernel(
    const float* __restrict__ t1, const float* __restrict__ t2,
    const float* __restrict__ t3, float* __restrict__ invn) {
  __shared__ float red[4];
  const float* t; int K;
  if (blockIdx.x == 0)      { t = t1; K = 4608; }
  else if (blockIdx.x == 1) { t = t2; K = 2304; }
  else                      { t = t3; K = 512;  }
  float ss = 0.f;
  for (int j = threadIdx.x; j < K; j += 256) { float v = t[j]; ss += v * v; }
  ss = blk_sum256(ss, red);
  if (threadIdx.x == 0) invn[blockIdx.x] = 1.0f / (sqrtf(ss) + 1e-12f);
}

// ==== st = W t (wave per row) ====
__global__ __launch_bounds__(256) void snB_kernel(
    const float* __restrict__ w1, const float* __restrict__ t1,
    const float* __restrict__ w2, const float* __restrict__ t2,
    const float* __restrict__ w3, const float* __restrict__ t3,
    float* __restrict__ st) {
  int blk = blockIdx.x;                // 192 blocks: w*64 + rowgrp
  int w = blk >> 6;
  const float* W; const float* t; int K;
  if (w == 0)      { W = w1; t = t1; K = 4608; }
  else if (w == 1) { W = w2; t = t2; K = 2304; }
  else             { W = w3; t = t3; K = 512;  }
  int lane = threadIdx.x & 63, wave = threadIdx.x >> 6;
  int row = (blk & 63) * 4 + wave;
  const float* Wr = W + (size_t)row * K;
  float a = 0.f;
  for (int j = lane; j < K; j += 64) a += Wr[j] * t[j];
#pragma unroll
  for (int o = 32; o > 0; o >>= 1) a += __shfl_down(a, o, 64);
  if (lane == 0) st[w * 256 + row] = a;
}

// ==== sigma -> inv_sig ====
__global__ __launch_bounds__(256) void snC_kernel(
    const float* __restrict__ st, const float* __restrict__ invn,
    float* __restrict__ inv_sig) {
  __shared__ float red[4];
  int w = blockIdx.x;
  float v = st[w * 256 + threadIdx.x];
  float ss = blk_sum256(v * v, red);
  if (threadIdx.x == 0) {
    float in = invn[w];
    float s2 = in * in * ss;            // ||s||^2
    float sn = in * sqrtf(ss);          // ||s||
    float sigma = s2 / (sn + 1e-12f);
    inv_sig[w] = 1.0f / sigma;
  }
}

// ---- cast x / pre to bf16 (same [c][n] layout) ----
__global__ __launch_bounds__(256) void cast_xp_kernel(
    const float* __restrict__ x, const float* __restrict__ pre,
    unsigned short* __restrict__ xb, unsigned short* __restrict__ pb) {
  int i = blockIdx.x * 256 + threadIdx.x;   // 8 elems per thread
  const float* s = blockIdx.y ? pre : x;
  unsigned short* d = blockIdx.y ? pb : xb;
  float4 v0 = ((const float4*)s)[i * 2];
  float4 v1 = ((const float4*)s)[i * 2 + 1];
  bh8 o = { f2bf(v0.x), f2bf(v0.y), f2bf(v0.z), f2bf(v0.w),
            f2bf(v1.x), f2bf(v1.y), f2bf(v1.z), f2bf(v1.w) };
  *(bh8*)&d[(size_t)i * 8] = o;
}

// ---- conv weights OIHW -> [tap][cichunk][co][ci32], bf16 (coalesced B-op) ----
__global__ __launch_bounds__(256) void transpose_w_kernel(
    const float* __restrict__ src, unsigned short* __restrict__ dst, int Cin) {
  int i = blockIdx.x * 256 + threadIdx.x;   // linear over 9*256*Cin
  int ciin = i & 31;
  int co = (i >> 5) & 255;
  int rest = i >> 13;                       // t*nchunk + cc
  int nchunk = Cin >> 5;
  int cc = rest % nchunk;
  int t = rest / nchunk;
  int ci = (cc << 5) + ciin;
  dst[i] = (unsigned short)f2bf(src[((size_t)co * Cin + ci) * 9 + t]);
}

// ---- cast by_w [256][512] to bf16 ----
__global__ __launch_bounds__(256) void cast_w3_kernel(
    const float* __restrict__ src, unsigned short* __restrict__ dst) {
  int i = blockIdx.x * 256 + threadIdx.x;   // 8 elems per thread
  float4 v0 = ((const float4*)src)[i * 2];
  float4 v1 = ((const float4*)src)[i * 2 + 1];
  bh8 o = { f2bf(v0.x), f2bf(v0.y), f2bf(v0.z), f2bf(v0.w),
            f2bf(v1.x), f2bf(v1.y), f2bf(v1.z), f2bf(v1.w) };
  *(bh8*)&dst[(size_t)i * 8] = o;
}

// ---- fused q = qw*x (1x1 conv) -> qt [n][64] bf16, MFMA ----
// Per block: 64 n-rows, full cq=64, K=256 split 4 waves x 64c (2 chunks).
// A = x^T staged via scalar LDS transpose; B = qw cast inline to bf16.
__global__ __launch_bounds__(256, 2) void qgemm_kernel(
    const unsigned short* __restrict__ xb, const float* __restrict__ qw,
    unsigned short* __restrict__ qt) {
  int b = blockIdx.y;
  int n0 = blockIdx.x * 64;
  __shared__ short smem[24576];      // 48 KB (staging 32 KB; reduce reuse)
  int tid = threadIdx.x;
  int wave = tid >> 6, lane = tid & 63;
  short* Wt = smem + wave * 4096;
  short* Xt = Wt + 2048;
  int ln = lane & 15, qd = lane >> 4;
  int part = lane & 3, r4 = lane >> 2;
  int cl = lane >> 1, ng = lane & 1;
  f4 z = {0.f, 0.f, 0.f, 0.f};
  f4 acc[4][4];
#pragma unroll
  for (int i = 0; i < 4; ++i)
#pragma unroll
    for (int j = 0; j < 4; ++j) acc[i][j] = z;
#pragma unroll
  for (int kc = 0; kc < 2; ++kc) {
    int cc = wave * 2 + kc;
    int c0c = cc << 5;
    // stage weight chunk [cq=64][c=32] bf16 (cast f32 inline)
#pragma unroll
    for (int t2 = 0; t2 < 4; ++t2) {
      int rr = r4 + t2 * 16;
      const float* wp = &qw[rr * 256 + c0c + part * 8];
      float4 v0 = *(const float4*)wp;
      float4 v1 = *(const float4*)(wp + 4);
      bh8 o = { f2bf(v0.x), f2bf(v0.y), f2bf(v0.z), f2bf(v0.w),
                f2bf(v1.x), f2bf(v1.y), f2bf(v1.z), f2bf(v1.w) };
      *(bh8*)&Wt[rr * 32 + SWCOL(rr, part * 8)] = o;
    }
    // stage x^T chunk [n=64][c=32] via scalar transpose (reads coalesced)
#pragma unroll
    for (int it = 0; it < 4; ++it) {
      int gg = ng + it * 2;
      bh8 v = *(const bh8*)&xb[((size_t)(b * 256 + c0c + cl) << 12) + n0 + gg * 8];
#pragma unroll
      for (int e = 0; e < 8; ++e) {
        int nl = gg * 8 + e;
        Xt[nl * 32 + (cl ^ (((nl >> 1) & 3) << 3))] = v[e];
      }
    }
    // wave-synchronous MFMA (same-wave ds_write -> ds_read)
    bh8 bw[4];
#pragma unroll
    for (int j = 0; j < 4; ++j) {
      int row = j * 16 + ln;
      bw[j] = *(const bh8*)&Wt[row * 32 + SWCOL(row, qd * 8)];
    }
#pragma unroll
    for (int i = 0; i < 4; ++i) {
      int row = i * 16 + ln;
      bh8 a = *(const bh8*)&Xt[row * 32 + SWCOL(row, qd * 8)];
#pragma unroll
      for (int j = 0; j < 4; ++j)
        acc[i][j] = __builtin_amdgcn_mfma_f32_16x16x32_bf16(a, bw[j], acc[i][j], 0, 0, 0);
    }
  }
  // cross-wave reduction: wave j owns cq subtile j
  float* red = (float*)smem;
  __syncthreads();
#pragma unroll
  for (int j = 0; j < 4; ++j) {
    if (j == wave) continue;
    int s = wave - (wave > j ? 1 : 0);
#pragma unroll
    for (int i = 0; i < 4; ++i)
      *(f4*)&red[((((j * 3 + s) << 2) + i) << 8) + (lane << 2)] = acc[i][j];
  }
  __syncthreads();
#pragma unroll
  for (int j = 0; j < 4; ++j) {
    if (j != wave) continue;
#pragma unroll
    for (int s = 0; s < 3; ++s)
#pragma unroll
      for (int i = 0; i < 4; ++i) {
        f4 v = *(const f4*)&red[((((j * 3 + s) << 2) + i) << 8) + (lane << 2)];
        acc[i][j][0] += v[0]; acc[i][j][1] += v[1];
        acc[i][j][2] += v[2]; acc[i][j][3] += v[3];
      }
  }
  // epilogue: qt[b][n][cq], wave writes cq subtile == wave
#pragma unroll
  for (int j = 0; j < 4; ++j) {
    if (j != wave) continue;
#pragma unroll
    for (int i = 0; i < 4; ++i) {
      int n = n0 + i * 16 + qd * 4;
#pragma unroll
      for (int r = 0; r < 4; ++r)
        qt[((size_t)(b * 4096 + n + r) << 6) + j * 16 + ln] =
            (unsigned short)f2bf(acc[i][j][r]);
    }
  }
}

// ---- energy via MFMA bf16: 128x128 tile, 4 waves (2x2), K=64 ----
__global__ __launch_bounds__(256, 4) void energy_mfma_kernel(
    const unsigned short* __restrict__ qt, float* __restrict__ att) {
  int b = blockIdx.z;
  int n0 = blockIdx.x << 7;
  int m0 = blockIdx.y << 7;
  __shared__ short Qn[128 * 64];
  __shared__ short Qm[128 * 64];
  int tid = threadIdx.x;
  int wave = tid >> 6, lane = tid & 63;
  int ln = lane & 15, qd = lane >> 4;
  int wy = wave >> 1, wx = wave & 1;
  int g = tid & 7, row0 = tid >> 3;         // 8 granules x 32 rows
#pragma unroll
  for (int it = 0; it < 4; ++it) {
    int r = row0 + it * 32;
    int colb = ((g ^ (r & 7)) << 3);
    *(bh8*)&Qn[(r << 6) + colb] =
        *(const bh8*)&qt[((size_t)(b * 4096 + n0 + r) << 6) + (g << 3)];
    *(bh8*)&Qm[(r << 6) + colb] =
        *(const bh8*)&qt[((size_t)(b * 4096 + m0 + r) << 6) + (g << 3)];
  }
  __syncthreads();
  f4 z = {0.f, 0.f, 0.f, 0.f};
  f4 acc[4][4];
#pragma unroll
  for (int i = 0; i < 4; ++i)
#pragma unroll
    for (int j = 0; j < 4; ++j) acc[i][j] = z;
#pragma unroll
  for (int kc = 0; kc < 2; ++kc) {
    bh8 am[4];
#pragma unroll
    for (int j = 0; j < 4; ++j) {
      int row = wx * 64 + j * 16 + ln;
      int colb = (((qd + (kc << 2)) ^ (row & 7)) << 3);
      am[j] = *(const bh8*)&Qm[(row << 6) + colb];
    }
#pragma unroll
    for (int i = 0; i < 4; ++i) {
      int row = wy * 64 + i * 16 + ln;
      int colb = (((qd + (kc << 2)) ^ (row & 7)) << 3);
      bh8 an = *(const bh8*)&Qn[(row << 6) + colb];
#pragma unroll
      for (int j = 0; j < 4; ++j)
        acc[i][j] = __builtin_amdgcn_mfma_f32_16x16x32_bf16(an, am[j], acc[i][j], 0, 0, 0);
    }
  }
  size_t base = ((size_t)b << 24);
#pragma unroll
  for (int i = 0; i < 4; ++i) {
    int n = n0 + wy * 64 + i * 16 + qd * 4;
#pragma unroll
    for (int j = 0; j < 4; ++j) {
      int m = m0 + wx * 64 + j * 16 + ln;
#pragma unroll
      for (int r = 0; r < 4; ++r)
        att[base + (((size_t)(n + r)) << 12) + m] = acc[i][j][r];
    }
  }
}

// ---- softmax in place over last dim 4096 ----
__global__ __launch_bounds__(256) void softmax_kernel(float* __restrict__ att) {
  __shared__ float red[4];
  size_t row = blockIdx.x;
  float4* rp4 = (float4*)(att + (row << 12));
  int tid = threadIdx.x;
  float4 v[4];
#pragma unroll
  for (int i = 0; i < 4; ++i) v[i] = rp4[tid + (i << 8)];
  float mx = -INFINITY;
#pragma unroll
  for (int i = 0; i < 4; ++i)
    mx = fmaxf(mx, fmaxf(fmaxf(v[i].x, v[i].y), fmaxf(v[i].z, v[i].w)));
  mx = blk_max256(mx, red);
  float s = 0.f;
#pragma unroll
  for (int i = 0; i < 4; ++i) {
    v[i].x = __expf(v[i].x - mx); v[i].y = __expf(v[i].y - mx);
    v[i].z = __expf(v[i].z - mx); v[i].w = __expf(v[i].w - mx);
    s += v[i].x + v[i].y + v[i].z + v[i].w;
  }
  s = blk_sum256(s, red);
  float inv = 1.0f / s;
#pragma unroll
  for (int i = 0; i < 4; ++i) {
    v[i].x *= inv; v[i].y *= inv; v[i].z *= inv; v[i].w *= inv;
    rp4[tid + (i << 8)] = v[i];
  }
}

// ---- fused out/cf MFMA GEMM: 4 waves, k-split, 1-deep T14 prefetch ----
// Exact r4 structure (measured good: <83us, no spill). 2-D grid (64,4,2):
// the 4 blocks sharing each att row differ by 64 in linear bid, 64%8==0 ->
// same XCD L2 (r6's remap: FETCH 392MB). 1-deep prefetch: r7's 2-deep
// variant needed >128 arch-VGPRs beside 128 AGPR acc under the (256,2)
// 256-total cap -> spill (WRITE 259MB). Keep register count at r4 level.
__global__ __launch_bounds__(256, 2) void outcf_mfma_kernel(
    const unsigned short* __restrict__ xb, const unsigned short* __restrict__ pb,
    const float* __restrict__ x, const float* __restrict__ pre,
    const float* __restrict__ att, const float* __restrict__ mask,
    const float* __restrict__ gamma_p, const float* __restrict__ alpha_p,
    unsigned short* __restrict__ y_t) {
  int b = blockIdx.z;
  int c0 = blockIdx.y * 64;
  int j0 = blockIdx.x * 64;
  __shared__ short smem[12 * 64 * 32];   // 49152 B: 4 waves x (Xs,Ps,As) 64x32
  int tid = threadIdx.x;
  int wave = tid >> 6, lane = tid & 63;
  short* Xs = smem + wave * (3 * 2048);
  short* Ps = Xs + 2048;
  short* As = Ps + 2048;
  int ln = lane & 15, qd = lane >> 4;
  f4 z = {0.f, 0.f, 0.f, 0.f};
  f4 accO[4][4], accC[4][4];
#pragma unroll
  for (int i = 0; i < 4; ++i)
#pragma unroll
    for (int j = 0; j < 4; ++j) { accO[i][j] = z; accC[i][j] = z; }
  int part = lane & 3, r4 = lane >> 2;
  int part8 = lane & 7, r8 = lane >> 3;
  int kb = wave << 10;                       // 1024 k per wave
  bh8 xr[4], pr[4];
  float4 ar[8];
  // prologue: prefetch it=0
#pragma unroll
  for (int t2 = 0; t2 < 4; ++t2) {
    int rr = r4 + t2 * 16;
    xr[t2] = *(const bh8*)&xb[((size_t)(b * 256 + c0 + rr) << 12) + kb + part * 8];
    pr[t2] = *(const bh8*)&pb[((size_t)(b * 256 + c0 + rr) << 12) + kb + part * 8];
  }
#pragma unroll
  for (int t2 = 0; t2 < 8; ++t2) {
    int rr = r8 + t2 * 8;
    ar[t2] = *(const float4*)&att[((size_t)b << 24) + ((size_t)(j0 + rr) << 12) + kb + part8 * 4];
  }
  for (int it = 0; it < 32; ++it) {
    int k0 = kb + (it << 5);
    // write staged regs to LDS (wave-synchronous)
#pragma unroll
    for (int t2 = 0; t2 < 4; ++t2) {
      int rr = r4 + t2 * 16;
      int col = SWCOL(rr, part * 8);
      *(bh8*)&Xs[rr * 32 + col] = xr[t2];
      *(bh8*)&Ps[rr * 32 + col] = pr[t2];
    }
#pragma unroll
    for (int t2 = 0; t2 < 8; ++t2) {
      int rr = r8 + t2 * 8;
      int col = SWCOL(rr, part8 * 4);
      float4 v = ar[t2];
      bh4 o = { f2bf(v.x), f2bf(v.y), f2bf(v.z), f2bf(v.w) };
      *(bh4*)&As[rr * 32 + col] = o;
    }
    // issue next-iteration loads (hidden under MFMA loop)
    if (it + 1 < 32) {
      int k1 = k0 + 32;
#pragma unroll
      for (int t2 = 0; t2 < 4; ++t2) {
        int rr = r4 + t2 * 16;
        xr[t2] = *(const bh8*)&xb[((size_t)(b * 256 + c0 + rr) << 12) + k1 + part * 8];
        pr[t2] = *(const bh8*)&pb[((size_t)(b * 256 + c0 + rr) << 12) + k1 + part * 8];
      }
#pragma unroll
      for (int t2 = 0; t2 < 8; ++t2) {
        int rr = r8 + t2 * 8;
        ar[t2] = *(const float4*)&att[((size_t)b << 24) + ((size_t)(j0 + rr) << 12) + k1 + part8 * 4];
      }
    }
    bh8 bf[4];
#pragma unroll
    for (int j = 0; j < 4; ++j) {
      int row = j * 16 + ln;
      bf[j] = *(const bh8*)&As[row * 32 + SWCOL(row, qd * 8)];
    }
#pragma unroll
    for (int i = 0; i < 4; ++i) {
      int row = i * 16 + ln;
      int col = SWCOL(row, qd * 8);
      bh8 ax = *(const bh8*)&Xs[row * 32 + col];
      bh8 ap = *(const bh8*)&Ps[row * 32 + col];
#pragma unroll
      for (int j = 0; j < 4; ++j) {
        accO[i][j] = __builtin_amdgcn_mfma_f32_16x16x32_bf16(ax, bf[j], accO[i][j], 0, 0, 0);
        accC[i][j] = __builtin_amdgcn_mfma_f32_16x16x32_bf16(ap, bf[j], accC[i][j], 0, 0, 0);
      }
    }
  }
  // ---- cross-wave k-reduction: wave j owns column block j ----
  float* red = (float*)smem;
  __syncthreads();
#pragma unroll
  for (int j = 0; j < 4; ++j) {
    if (j == wave) continue;
    int s = wave - (wave > j ? 1 : 0);
#pragma unroll
    for (int i = 0; i < 4; ++i)
      *(f4*)&red[((((j * 3 + s) << 2) + i) << 8) + (lane << 2)] = accO[i][j];
  }
  __syncthreads();
#pragma unroll
  for (int j = 0; j < 4; ++j) {
    if (j != wave) continue;
#pragma unroll
    for (int s = 0; s < 3; ++s)
#pragma unroll
      for (int i = 0; i < 4; ++i) {
        f4 v = *(const f4*)&red[((((j * 3 + s) << 2) + i) << 8) + (lane << 2)];
        accO[i][j][0] += v[0]; accO[i][j][1] += v[1];
        accO[i][j][2] += v[2]; accO[i][j][3] += v[3];
      }
  }
  __syncthreads();
#pragma unroll
  for (int j = 0; j < 4; ++j) {
    if (j == wave) continue;
    int s = wave - (wave > j ? 1 : 0);
#pragma unroll
    for (int i = 0; i < 4; ++i)
      *(f4*)&red[((((j * 3 + s) << 2) + i) << 8) + (lane << 2)] = accC[i][j];
  }
  __syncthreads();
#pragma unroll
  for (int j = 0; j < 4; ++j) {
    if (j != wave) continue;
#pragma unroll
    for (int s = 0; s < 3; ++s)
#pragma unroll
      for (int i = 0; i < 4; ++i) {
        f4 v = *(const f4*)&red[((((j * 3 + s) << 2) + i) << 8) + (lane << 2)];
        accC[i][j][0] += v[0]; accC[i][j][1] += v[1];
        accC[i][j][2] += v[2]; accC[i][j][3] += v[3];
      }
  }
  // ---- epilogue: wave handles j == wave ----
  float g = gamma_p[0], al = alpha_p[0];
#pragma unroll
  for (int j = 0; j < 4; ++j) {
    if (j != wave) continue;
    int jp = j0 + j * 16 + ln;
    float mv = mask[(b << 12) + jp];
#pragma unroll
    for (int i = 0; i < 4; ++i) {
      int cb = c0 + i * 16 + qd * 4;
      bh4 oY, oC;
#pragma unroll
      for (int r = 0; r < 4; ++r) {
        float xo = x[((size_t)(b * 256 + cb + r) << 12) + jp];
        float po = pre[((size_t)(b * 256 + cb + r) << 12) + jp];
        oY[r] = f2bf(g * accO[i][j][r] + xo);
        oC[r] = f2bf(al * (1.f - mv) * accC[i][j][r] + mv * po);
      }
      size_t rowb = ((size_t)b * 4096 + jp) * 512;
      *(bh4*)&y_t[rowb + cb] = oY;
      *(bh4*)&y_t[rowb + 256 + cb] = oC;
    }
  }
}

// ---- BN stats phase 1 ----
__global__ __launch_bounds__(256) void bn_part_kernel(
    const void* __restrict__ src, int isbf, int C, int rows_per_slab,
    float* __restrict__ part) {
  int slab = blockIdx.x;
  int r0 = slab * rows_per_slab;
  for (int co = threadIdx.x; co < C; co += 256) {
    float s = 0.f, ss = 0.f;
    if (isbf) {
      const unsigned short* p = (const unsigned short*)src;
      for (int r = 0; r < rows_per_slab; ++r) {
        float v = bf2f(p[(size_t)(r0 + r) * C + co]); s += v; ss += v * v;
      }
    } else {
      const float* p = (const float*)src;
      for (int r = 0; r < rows_per_slab; ++r) {
        float v = p[(size_t)(r0 + r) * C + co]; s += v; ss += v * v;
      }
    }
    part[(size_t)(slab * 2) * C + co] = s;
    part[(size_t)(slab * 2 + 1) * C + co] = ss;
  }
}

// ---- BN stats phase 2 ----
__global__ __launch_bounds__(256) void bn_finish_kernel(
    const float* __restrict__ part, int C, int slabs, float inv_count,
    float* __restrict__ mean, float* __restrict__ rstd) {
  for (int co = threadIdx.x; co < C; co += 256) {
    float s = 0.f, ss = 0.f;
    for (int sl = 0; sl < slabs; ++sl) {
      s += part[(size_t)(sl * 2) * C + co];
      ss += part[(size_t)(sl * 2 + 1) * C + co];
    }
    float m = s * inv_count;
    float var = ss * inv_count - m * m;
    mean[co] = m;
    rstd[co] = rsqrtf(var + 1e-5f);
  }
}

// ---- BN apply + leaky, bf16 -> bf16 ([n][C] layout) ----
__global__ __launch_bounds__(256) void bn_act_bf_kernel(
    const unsigned short* __restrict__ src, unsigned short* __restrict__ dst,
    const float* __restrict__ mean, const float* __restrict__ rstd,
    const float* __restrict__ sc, const float* __restrict__ bi, int Cm1) {
  int i = blockIdx.x * 256 + threadIdx.x;   // 4 elems
  int ch = (i * 4) & Cm1;
  bh4 v = *(const bh4*)&src[(size_t)i * 4];
  bh4 o;
#pragma unroll
  for (int e = 0; e < 4; ++e) {
    int c = ch + e;
    float a = rstd[c] * sc[c];
    float bb = bi[c] - mean[c] * a;
    float f = bf2f((unsigned short)v[e]) * a + bb;
    f = f > 0.f ? f : 0.01f * f;
    o[e] = f2bf(f);
  }
  *(bh4*)&dst[(size_t)i * 4] = o;
}

// ---- BN apply + leaky, f32 -> bf16 ----
__global__ __launch_bounds__(256) void bn_act_f_kernel(
    const float* __restrict__ src, unsigned short* __restrict__ dst,
    const float* __restrict__ mean, const float* __restrict__ rstd,
    const float* __restrict__ sc, const float* __restrict__ bi, int Cm1) {
  int i = blockIdx.x * 256 + threadIdx.x;   // 4 elems
  int ch = (i * 4) & Cm1;
  float4 v = ((const float4*)src)[i];
  float vv[4] = {v.x, v.y, v.z, v.w};
  bh4 o;
#pragma unroll
  for (int e = 0; e < 4; ++e) {
    int c = ch + e;
    float a = rstd[c] * sc[c];
    float bb = bi[c] - mean[c] * a;
    float f = vv[e] * a + bb;
    f = f > 0.f ? f : 0.01f * f;
    o[e] = f2bf(f);
  }
  *(bh4*)&dst[(size_t)i * 4] = o;
}

// ---- 3x3 conv: 9 accumulated MFMA GEMMs, 4 waves k-split, T14 prefetch ----
__global__ __launch_bounds__(256, 2) void conv3x3_mfma_kernel(
    const unsigned short* __restrict__ act_t, const unsigned short* __restrict__ wt,
    const float* __restrict__ inv_sig, int sidx, int Cin, int mode,
    float* __restrict__ out) {
  int b = blockIdx.z;
  int co0 = blockIdx.y * 64;
  int n0 = blockIdx.x * 64;
  __shared__ short smem[4 * 194 * 32];   // 49664 B, per-wave act tiles
  int tid = threadIdx.x;
  int wave = tid >> 6, lane = tid & 63;
  short* act_s = smem + wave * (194 * 32);
  int ln = lane & 15, qd = lane >> 4;
  int part = lane & 3, r4 = lane >> 2;
  f4 z = {0.f, 0.f, 0.f, 0.f};
  f4 acc[4][4];
#pragma unroll
  for (int i = 0; i < 4; ++i)
#pragma unroll
    for (int j = 0; j < 4; ++j) acc[i][j] = z;
  bh8 zf = {};
  int nchunk = Cin >> 5;
  int per = nchunk >> 2;                 // chunks per wave
  size_t tstride = (size_t)nchunk * 256 * 32;   // weight tap stride
  int cc0 = wave * per;
  bh8 sreg[13];
  // prologue: prefetch chunk cc0 act into regs
#pragma unroll
  for (int it = 0; it < 13; ++it) {
    int rr = r4 + it * 16;
    bh8 v = {};
    if (rr < 194) {
      int flat = n0 - 65 + rr;
      if ((unsigned)flat < 4096u)
        v = *(const bh8*)&act_t[((size_t)(b * 4096 + flat)) * Cin + (cc0 << 5) + part * 8];
    }
    sreg[it] = v;
  }
  for (int itc = 0; itc < per; ++itc) {
    int cc = cc0 + itc;
    // write staged act to LDS (wave-synchronous, no barrier)
#pragma unroll
    for (int it = 0; it < 13; ++it) {
      int rr = r4 + it * 16;
      if (rr < 194)
        *(bh8*)&act_s[rr * 32 + SWCOL(rr, part * 8)] = sreg[it];
    }
    // issue next chunk's act loads (hidden under the 9-tap MFMA loop)
    if (itc + 1 < per) {
      int ci0n = (cc + 1) << 5;
#pragma unroll
      for (int it = 0; it < 13; ++it) {
        int rr = r4 + it * 16;
        bh8 v = {};
        if (rr < 194) {
          int flat = n0 - 65 + rr;
          if ((unsigned)flat < 4096u)
            v = *(const bh8*)&act_t[((size_t)(b * 4096 + flat)) * Cin + ci0n + part * 8];
        }
        sreg[it] = v;
      }
    }
    // weights: [t][cc][co][ci32] layout, contiguous per (t,cc,j)
    const unsigned short* wb0 = wt + ((size_t)cc * 256) * 32;
    bh8 bwc[4], bwn[4];
#pragma unroll
    for (int j = 0; j < 4; ++j)
      bwc[j] = *(const bh8*)&wb0[(size_t)(co0 + j * 16 + ln) * 32 + qd * 8];
#pragma unroll
    for (int t = 0; t < 9; ++t) {
      if (t < 8) {
        const unsigned short* wbn = wb0 + (size_t)(t + 1) * tstride;
#pragma unroll
        for (int j = 0; j < 4; ++j)
          bwn[j] = *(const bh8*)&wbn[(size_t)(co0 + j * 16 + ln) * 32 + qd * 8];
      }
      int dy = t / 3, dx = t - dy * 3;
      int off = (dy - 1) * 64 + (dx - 1);
#pragma unroll
      for (int i = 0; i < 4; ++i) {
        int px = i * 16 + ln;
        int row = 65 + off + px;
        bh8 a = *(const bh8*)&act_s[row * 32 + SWCOL(row, qd * 8)];
        if (dx == 0 && px == 0) a = zf;
        if (dx == 2 && px == 63) a = zf;
#pragma unroll
        for (int j = 0; j < 4; ++j)
          acc[i][j] = __builtin_amdgcn_mfma_f32_16x16x32_bf16(a, bwc[j], acc[i][j], 0, 0, 0);
      }
      if (t < 8) {
#pragma unroll
        for (int j = 0; j < 4; ++j) bwc[j] = bwn[j];
      }
    }
  }
  // ---- cross-wave reduction: wave j owns column block j ----
  float* red = (float*)smem;
  __syncthreads();
#pragma unroll
  for (int j = 0; j < 4; ++j) {
    if (j == wave) continue;
    int s = wave - (wave > j ? 1 : 0);
#pragma unroll
    for (int i = 0; i < 4; ++i)
      *(f4*)&red[((((j * 3 + s) << 2) + i) << 8) + (lane << 2)] = acc[i][j];
  }
  __syncthreads();
#pragma unroll
  for (int j = 0; j < 4; ++j) {
    if (j != wave) continue;
#pragma unroll
    for (int s = 0; s < 3; ++s)
#pragma unroll
      for (int i = 0; i < 4; ++i) {
        f4 v = *(const f4*)&red[((((j * 3 + s) << 2) + i) << 8) + (lane << 2)];
        acc[i][j][0] += v[0]; acc[i][j][1] += v[1];
        acc[i][j][2] += v[2]; acc[i][j][3] += v[3];
      }
  }
  float isg = inv_sig[sidx];
  if (mode == 0) {
#pragma unroll
    for (int j = 0; j < 4; ++j) {
      if (j != wave) continue;
      int co = co0 + j * 16 + ln;
#pragma unroll
      for (int i = 0; i < 4; ++i) {
        int pb = n0 + i * 16 + qd * 4;
#pragma unroll
        for (int r = 0; r < 4; ++r)
          out[((size_t)(b * 4096 + pb + r)) * 256 + co] = acc[i][j][r] * isg;
      }
    }
  } else {
#pragma unroll
    for (int j = 0; j < 4; ++j) {
      if (j != wave) continue;
      int co = co0 + j * 16 + ln;
#pragma unroll
      for (int i = 0; i < 4; ++i) {
        int pb = n0 + i * 16 + qd * 4;
        float4* rp = (float4*)&out[((size_t)(b * 256 + co) << 12) + pb];
        float4 v = *rp;
        v.x += acc[i][j][0] * isg; v.y += acc[i][j][1] * isg;
        v.z += acc[i][j][2] * isg; v.w += acc[i][j][3] * isg;
        *rp = v;
      }
    }
  }
}

// ---- shortcut 1x1, 4 waves split K=512, T14 prefetch ----
__global__ __launch_bounds__(256, 2) void scgemm_mfma_kernel(
    const unsigned short* __restrict__ y_t, const unsigned short* __restrict__ w3b,
    const float* __restrict__ inv_sig, float* __restrict__ res) {
  int b = blockIdx.z;
  int co0 = blockIdx.y * 64;
  int n0 = blockIdx.x * 64;
  __shared__ short smem[24576];          // 49152 B (staging uses first 16 KB)
  int tid = threadIdx.x;
  int wave = tid >> 6, lane = tid & 63;
  short* Ys = smem + wave * 2048;
  int ln = lane & 15, qd = lane >> 4;
  int part = lane & 3, r4 = lane >> 2;
  f4 z = {0.f, 0.f, 0.f, 0.f};
  f4 acc[4][4];
#pragma unroll
  for (int i = 0; i < 4; ++i)
#pragma unroll
    for (int j = 0; j < 4; ++j) acc[i][j] = z;
  int kb = wave << 7;                    // 128 k per wave
  bh8 ys[4], bwc[4], yn[4], bwn[4];
#pragma unroll
  for (int t2 = 0; t2 < 4; ++t2) {
    int rr = r4 + t2 * 16;
    ys[t2] = *(const bh8*)&y_t[((size_t)(b * 4096 + n0 + rr)) * 512 + kb + part * 8];
  }
#pragma unroll
  for (int j = 0; j < 4; ++j)
    bwc[j] = *(const bh8*)&w3b[((size_t)(co0 + j * 16 + ln)) * 512 + kb + qd * 8];
#pragma unroll
  for (int it = 0; it < 4; ++it) {
    int k0 = kb + (it << 5);
#pragma unroll
    for (int t2 = 0; t2 < 4; ++t2) {
      int rr = r4 + t2 * 16;
      *(bh8*)&Ys[rr * 32 + SWCOL(rr, part * 8)] = ys[t2];
    }
    if (it < 3) {
      int k1 = k0 + 32;
#pragma unroll
      for (int t2 = 0; t2 < 4; ++t2) {
        int rr = r4 + t2 * 16;
        yn[t2] = *(const bh8*)&y_t[((size_t)(b * 4096 + n0 + rr)) * 512 + k1 + part * 8];
      }
#pragma unroll
      for (int j = 0; j < 4; ++j)
        bwn[j] = *(const bh8*)&w3b[((size_t)(co0 + j * 16 + ln)) * 512 + k1 + qd * 8];
    }
#pragma unroll
    for (int i = 0; i < 4; ++i) {
      int row = i * 16 + ln;
      bh8 a = *(const bh8*)&Ys[row * 32 + SWCOL(row, qd * 8)];
#pragma unroll
      for (int j = 0; j < 4; ++j)
        acc[i][j] = __builtin_amdgcn_mfma_f32_16x16x32_bf16(a, bwc[j], acc[i][j], 0, 0, 0);
    }
    if (it < 3) {
#pragma unroll
      for (int t2 = 0; t2 < 4; ++t2) ys[t2] = yn[t2];
#pragma unroll
      for (int j = 0; j < 4; ++j) bwc[j] = bwn[j];
    }
  }
  // ---- cross-wave reduction: wave j owns column block j ----
  float* red = (float*)smem;
  __syncthreads();
#pragma unroll
  for (int j = 0; j < 4; ++j) {
    if (j == wave) continue;
    int s = wave - (wave > j ? 1 : 0);
#pragma unroll
    for (int i = 0; i < 4; ++i)
      *(f4*)&red[((((j * 3 + s) << 2) + i) << 8) + (lane << 2)] = acc[i][j];
  }
  __syncthreads();
#pragma unroll
  for (int j = 0; j < 4; ++j) {
    if (j != wave) continue;
#pragma unroll
    for (int s = 0; s < 3; ++s)
#pragma unroll
      for (int i = 0; i < 4; ++i) {
        f4 v = *(const f4*)&red[((((j * 3 + s) << 2) + i) << 8) + (lane << 2)];
        acc[i][j][0] += v[0]; acc[i][j][1] += v[1];
        acc[i][j][2] += v[2]; acc[i][j][3] += v[3];
      }
  }
  float isg = inv_sig[2];
#pragma unroll
  for (int j = 0; j < 4; ++j) {
    if (j != wave) continue;
    int co = co0 + j * 16 + ln;
#pragma unroll
    for (int i = 0; i < 4; ++i) {
      int pb = n0 + i * 16 + qd * 4;
      float4 o;
      o.x = acc[i][j][0] * isg; o.y = acc[i][j][1] * isg;
      o.z = acc[i][j][2] * isg; o.w = acc[i][j][3] * isg;
      *(float4*)&res[((size_t)(b * 256 + co) << 12) + pb] = o;
    }
  }
}

extern "C" void kernel_launch(void* const* d_in, const int* in_sizes, int n_in,
                              void* d_out, int out_size, void* d_ws, size_t ws_size,
                              hipStream_t stream) {
  const float* x     = (const float*)d_in[0];
  const float* pre   = (const float*)d_in[1];
  const float* mask  = (const float*)d_in[2];
  const float* qw    = (const float*)d_in[3];
  const float* gamma = (const float*)d_in[4];
  const float* alpha = (const float*)d_in[5];
  const float* bn1s  = (const float*)d_in[6];
  const float* bn1b  = (const float*)d_in[7];
  const float* c1w   = (const float*)d_in[8];
  const float* u1    = (const float*)d_in[9];
  const float* bn2s  = (const float*)d_in[11];
  const float* bn2b  = (const float*)d_in[12];
  const float* c2w   = (const float*)d_in[13];
  const float* u2    = (const float*)d_in[14];
  const float* byw   = (const float*)d_in[16];
  const float* u3    = (const float*)d_in[17];

  float* res = (float*)d_out;                 // 2*256*4096
  float* att = res + (size_t)2 * 256 * 4096;  // 2*4096*4096

  char* W = (char*)d_ws;
  float* inv_sig = (float*)(W + 0);
  float* mean1   = (float*)(W + 64);
  float* rstd1   = (float*)(W + 2112);
  float* mean2   = (float*)(W + 4160);
  float* rstd2   = (float*)(W + 5184);
  float* part    = (float*)(W + 8192);            // 64*2*512 f32
  unsigned short* x_bf = (unsigned short*)(W + 2367488);
  unsigned short* p_bf = (unsigned short*)(W + 6561792);
  unsigned short* y_t  = (unsigned short*)(W + 10756096);   // [2][4096][512]
  unsigned short* act1 = (unsigned short*)(W + 19144704);   // [2][4096][512]
  float* h1_t          = (float*)(W + 27533312);            // [2][4096][256]
  unsigned short* act2 = (unsigned short*)(W + 35921920);   // [2][4096][256]
  unsigned short* w1t  = (unsigned short*)(W + 40116224);   // [9][16][256][32]
  unsigned short* w2t  = (unsigned short*)(W + 42475520);   // [9][8][256][32]
  unsigned short* w3b  = (unsigned short*)(W + 43655168);   // [256][512]
  float* t1      = (float*)(W + 43917312);        // 4608 f32
  float* t2      = (float*)(W + 43935744);        // 2304 f32
  float* t3      = (float*)(W + 43944960);        // 512 f32
  float* invn    = (float*)(W + 43947008);        // 3 f32
  float* st      = (float*)(W + 43947072);        // 768 f32
  // qt parks in act1's region (act1 is written only after energy completes)
  unsigned short* qt = (unsigned short*)(W + 19144704);     // [2][4096][64] bf16

  hipLaunchKernelGGL(snA_kernel, dim3(29), dim3(256), 0, stream,
                     c1w, u1, c2w, u2, byw, u3, t1, t2, t3);
  hipLaunchKernelGGL(snN_kernel, dim3(3), dim3(256), 0, stream, t1, t2, t3, invn);
  hipLaunchKernelGGL(snB_kernel, dim3(192), dim3(256), 0, stream,
                     c1w, t1, c2w, t2, byw, t3, st);
  hipLaunchKernelGGL(snC_kernel, dim3(3), dim3(256), 0, stream, st, invn, inv_sig);
  hipLaunchKernelGGL(cast_xp_kernel, dim3(1024, 2), dim3(256), 0, stream, x, pre, x_bf, p_bf);
  hipLaunchKernelGGL(transpose_w_kernel, dim3(4608), dim3(256), 0, stream, c1w, w1t, 512);
  hipLaunchKernelGGL(transpose_w_kernel, dim3(2304), dim3(256), 0, stream, c2w, w2t, 256);
  hipLaunchKernelGGL(cast_w3_kernel, dim3(64), dim3(256), 0, stream, byw, w3b);
  hipLaunchKernelGGL(qgemm_kernel, dim3(64, 2), dim3(256), 0, stream, x_bf, qw, qt);
  hipLaunchKernelGGL(energy_mfma_kernel, dim3(32, 32, 2), dim3(256), 0, stream, qt, att);
  hipLaunchKernelGGL(softmax_kernel, dim3(8192), dim3(256), 0, stream, att);
  hipLaunchKernelGGL(outcf_mfma_kernel, dim3(64, 4, 2), dim3(256), 0, stream,
                     x_bf, p_bf, x, pre, att, mask, gamma, alpha, y_t);
  hipLaunchKernelGGL(bn_part_kernel, dim3(64), dim3(256), 0, stream,
                     (const void*)y_t, 1, 512, 128, part);
  hipLaunchKernelGGL(bn_finish_kernel, dim3(1), dim3(256), 0, stream,
                     part, 512, 64, 1.0f / 8192.0f, mean1, rstd1);
  hipLaunchKernelGGL(bn_act_bf_kernel, dim3(8192), dim3(256), 0, stream,
                     y_t, act1, mean1, rstd1, bn1s, bn1b, 511);
  hipLaunchKernelGGL(conv3x3_mfma_kernel, dim3(64, 4, 2), dim3(256), 0, stream,
                     act1, w1t, inv_sig, 0, 512, 0, h1_t);
  hipLaunchKernelGGL(bn_part_kernel, dim3(64), dim3(256), 0, stream,
                     (const void*)h1_t, 0, 256, 128, part);
  hipLaunchKernelGGL(bn_finish_kernel, dim3(1), dim3(256), 0, stream,
                     part, 256, 64, 1.0f / 8192.0f, mean2, rstd2);
  hipLaunchKernelGGL(bn_act_f_kernel, dim3(2048), dim3(256), 0, stream,
                     h1_t, act2, mean2, rstd2, bn2s, bn2b, 255);
  hipLaunchKernelGGL(scgemm_mfma_kernel, dim3(64, 4, 2), dim3(256), 0, stream,
                     y_t, w3b, inv_sig, res);
  hipLaunchKernelGGL(conv3x3_mfma_kernel, dim3(64, 4, 2), dim3(256), 0, stream,
                     act2, w2t, inv_sig, 1, 256, 1, res);
}